// Round 1
// baseline (1170.272 us; speedup 1.0000x reference)
//
#include <hip/hip_runtime.h>

typedef __attribute__((ext_vector_type(8))) short bf16x8;
typedef __attribute__((ext_vector_type(4))) float f32x4;

constexpr int B_ = 8, Q_ = 512, HIST_ = 1536, HID_ = 4096, NH_ = 32, D_ = 128;
constexpr int BS_ = 64, NBLK_ = 32;
constexpr int T_ = B_ * Q_;            // 4096
constexpr int QKVN = (NH_ + 2) * D_;   // 4352
constexpr int KVC = NBLK_ * BS_;       // 2048

__device__ __forceinline__ unsigned short f2bf(float f) {
  union { float f; unsigned u; } v; v.f = f;
  unsigned r = v.u + 0x7FFFu + ((v.u >> 16) & 1u);
  return (unsigned short)(r >> 16);
}
__device__ __forceinline__ float bf2f(unsigned short s) {
  union { unsigned u; float f; } v; v.u = ((unsigned)s) << 16;
  return v.f;
}

// ---------------- f32 -> bf16 conversion (vectorized) ----------------
__global__ void k_conv(const float* __restrict__ in, unsigned short* __restrict__ out, int n4) {
  int i = blockIdx.x * blockDim.x + threadIdx.x;
  int stride = gridDim.x * blockDim.x;
  for (; i < n4; i += stride) {
    float4 v = reinterpret_cast<const float4*>(in)[i];
    ushort4 o;
    o.x = f2bf(v.x); o.y = f2bf(v.y); o.z = f2bf(v.z); o.w = f2bf(v.w);
    reinterpret_cast<ushort4*>(out)[i] = o;
  }
}

// ---------------- bf16 GEMM, C[i,j] = sum_k A[i,k]*B[j,k] (both K-major) ----------------
// 128x128 tile, BK=64, 4 waves (2x2), 16x16x32 MFMA, XOR-swizzled LDS.
__global__ void k_gemm_bt(const unsigned short* __restrict__ A,
                          const unsigned short* __restrict__ Bm,
                          float* __restrict__ Cf, unsigned short* __restrict__ Cb,
                          int M, int N, int K, int ldc) {
  __shared__ alignas(16) unsigned short lA[128 * 64];
  __shared__ alignas(16) unsigned short lB[128 * 64];
  const int tid = threadIdx.x;
  const int lane = tid & 63;
  const int w = tid >> 6;
  const int wr = w >> 1, wc = w & 1;
  const int n0 = blockIdx.x * 128, m0 = blockIdx.y * 128;
  const int lr = lane & 15, lk = lane >> 4;

  f32x4 acc[4][4];
#pragma unroll
  for (int m = 0; m < 4; ++m)
#pragma unroll
    for (int n = 0; n < 4; ++n) acc[m][n] = f32x4{0.f, 0.f, 0.f, 0.f};

  for (int k0 = 0; k0 < K; k0 += 64) {
    // stage A and B tiles (128 rows x 64 k) with XOR swizzle on 16B slots
#pragma unroll
    for (int c = 0; c < 4; ++c) {
      int e = c * 2048 + tid * 8;
      int row = e >> 6, col = e & 63;
      bf16x8 va = *reinterpret_cast<const bf16x8*>(A + (size_t)(m0 + row) * K + k0 + col);
      bf16x8 vb = *reinterpret_cast<const bf16x8*>(Bm + (size_t)(n0 + row) * K + k0 + col);
      int off = row * 64 + (((col >> 3) ^ (row & 7)) << 3);
      *reinterpret_cast<bf16x8*>(&lA[off]) = va;
      *reinterpret_cast<bf16x8*>(&lB[off]) = vb;
    }
    __syncthreads();
#pragma unroll
    for (int kk = 0; kk < 2; ++kk) {
      bf16x8 af[4], bfr[4];
      int slot = kk * 4 + lk;
#pragma unroll
      for (int m = 0; m < 4; ++m) {
        int row = wr * 64 + m * 16 + lr;
        af[m] = *reinterpret_cast<bf16x8*>(&lA[row * 64 + ((slot ^ (row & 7)) << 3)]);
      }
#pragma unroll
      for (int n = 0; n < 4; ++n) {
        int row = wc * 64 + n * 16 + lr;
        bfr[n] = *reinterpret_cast<bf16x8*>(&lB[row * 64 + ((slot ^ (row & 7)) << 3)]);
      }
#pragma unroll
      for (int m = 0; m < 4; ++m)
#pragma unroll
        for (int n = 0; n < 4; ++n)
          acc[m][n] = __builtin_amdgcn_mfma_f32_16x16x32_bf16(af[m], bfr[n], acc[m][n], 0, 0, 0);
    }
    __syncthreads();
  }
  // epilogue: C row = (lane>>4)*4+reg, col = lane&15
#pragma unroll
  for (int m = 0; m < 4; ++m)
#pragma unroll
    for (int n = 0; n < 4; ++n)
#pragma unroll
      for (int j = 0; j < 4; ++j) {
        int r = m0 + wr * 64 + m * 16 + lk * 4 + j;
        int c = n0 + wc * 64 + n * 16 + lr;
        if (Cb) Cb[(size_t)r * ldc + c] = f2bf(acc[m][n][j]);
        else Cf[(size_t)r * ldc + c] = acc[m][n][j];
      }
}

// ---------------- RoPE + repack: fused(T,4352) -> q[b,h,q,d], kseq/vseq[b,pos,d] ----------------
__global__ void k_rope(const unsigned short* __restrict__ fused,
                       const int* __restrict__ pos_ids,
                       unsigned short* __restrict__ qb,
                       unsigned short* __restrict__ kseq,
                       unsigned short* __restrict__ vseq) {
  int t = blockIdx.x;
  int d = threadIdx.x;  // 128 threads
  int b = t >> 9, q = t & 511;
  int pos = pos_ids[t];
  __shared__ float cs[64], sn[64];
  if (d < 64) {
    float inv = powf(10000.f, -(float)d * (1.f / 64.f));
    float ang = (float)pos * inv;
    cs[d] = cosf(ang);
    sn[d] = sinf(ang);
  }
  __syncthreads();
  float c = cs[d & 63], s = sn[d & 63];
  const unsigned short* row = fused + (size_t)t * QKVN;
#pragma unroll 4
  for (int h = 0; h < NH_; ++h) {
    float x = bf2f(row[h * D_ + d]);
    float xr = (d < 64) ? -bf2f(row[h * D_ + d + 64]) : bf2f(row[h * D_ + d - 64]);
    qb[(((size_t)(b * NH_ + h)) * Q_ + q) * D_ + d] = f2bf(x * c + xr * s);
  }
  {
    float x = bf2f(row[NH_ * D_ + d]);
    float xr = (d < 64) ? -bf2f(row[NH_ * D_ + d + 64]) : bf2f(row[NH_ * D_ + d - 64]);
    kseq[((size_t)b * KVC + pos) * D_ + d] = f2bf(x * c + xr * s);
  }
  vseq[((size_t)b * KVC + pos) * D_ + d] = row[(NH_ + 1) * D_ + d];
}

// ---------------- gather history KV from paged cache -> kseq/vseq (bf16) ----------------
__global__ void k_gather(const float* __restrict__ pk, const float* __restrict__ pv,
                         const int* __restrict__ bo,
                         unsigned short* __restrict__ kseq, unsigned short* __restrict__ vseq) {
  int i = blockIdx.x * blockDim.x + threadIdx.x;  // one float4 (4 d) per thread
  if (i >= B_ * HIST_ * (D_ / 4)) return;
  int d4 = i & 31;
  int p = (i >> 5) % HIST_;
  int b = i / (32 * HIST_);
  int blk = bo[b * NBLK_ + (p >> 6)];
  size_t src = ((size_t)blk * BS_ + (p & 63)) * D_ + d4 * 4;
  float4 kv = *reinterpret_cast<const float4*>(pk + src);
  float4 vv = *reinterpret_cast<const float4*>(pv + src);
  ushort4 ko, vo;
  ko.x = f2bf(kv.x); ko.y = f2bf(kv.y); ko.z = f2bf(kv.z); ko.w = f2bf(kv.w);
  vo.x = f2bf(vv.x); vo.y = f2bf(vv.y); vo.z = f2bf(vv.z); vo.w = f2bf(vv.w);
  size_t dst = ((size_t)b * KVC + p) * D_ + d4 * 4;
  *reinterpret_cast<ushort4*>(kseq + dst) = ko;
  *reinterpret_cast<ushort4*>(vseq + dst) = vo;
}

// ---------------- MQA flash attention ----------------
// block: 256 thr (4 waves), one (b,h), 64 q rows (16/wave); kv tiles of 64.
__global__ void k_attn(const unsigned short* __restrict__ qb,
                       const unsigned short* __restrict__ kseq,
                       const unsigned short* __restrict__ vseq,
                       const int* __restrict__ histL,
                       unsigned short* __restrict__ outb) {
  __shared__ alignas(16) unsigned short kl[64 * 136];   // K tile, row-padded
  __shared__ alignas(16) unsigned short vt[128 * 72];   // V^T tile, row-padded
  __shared__ alignas(16) unsigned short pl[4 * 16 * 72];// per-wave P tile
  const int qt = blockIdx.x, h = blockIdx.y, b = blockIdx.z;
  const int tid = threadIdx.x, lane = tid & 63, w = tid >> 6;
  const int lr = lane & 15, lk = lane >> 4;
  const int q0 = qt * 64;
  const int hist = histL[b];

  // Q fragments: wave w owns rows q0+w*16 .. +15
  const unsigned short* qbase = qb + (((size_t)(b * NH_ + h)) * Q_ + q0 + w * 16 + lr) * D_;
  bf16x8 aq[4];
#pragma unroll
  for (int f = 0; f < 4; ++f)
    aq[f] = *reinterpret_cast<const bf16x8*>(qbase + f * 32 + lk * 8);

  f32x4 o[8];
#pragma unroll
  for (int dn = 0; dn < 8; ++dn) o[dn] = f32x4{0.f, 0.f, 0.f, 0.f};
  float mrow[4], lsum[4];
#pragma unroll
  for (int r = 0; r < 4; ++r) { mrow[r] = -1e30f; lsum[r] = 0.f; }

  const int kvend = hist + q0 + 64;
  const int ntiles = (kvend + 63) >> 6;
  const float scale = 0.08838834764831845f;
  const int qposw = hist + q0 + w * 16 + lk * 4;  // pos of this lane's C row base

  for (int it = 0; it < ntiles; ++it) {
    int kv0 = it * 64;
    __syncthreads();
    // stage K tile (row-major, padded) and V tile transposed
#pragma unroll
    for (int cch = 0; cch < 4; ++cch) {
      int e = cch * 2048 + tid * 8;
      int krow = e >> 7, dcol = e & 127;
      size_t gsrc = ((size_t)b * KVC + kv0 + krow) * D_ + dcol;
      bf16x8 kv8 = *reinterpret_cast<const bf16x8*>(kseq + gsrc);
      *reinterpret_cast<bf16x8*>(&kl[krow * 136 + dcol]) = kv8;
      bf16x8 vv8 = *reinterpret_cast<const bf16x8*>(vseq + gsrc);
#pragma unroll
      for (int j = 0; j < 8; ++j) vt[(dcol + j) * 72 + krow] = (unsigned short)vv8[j];
    }
    __syncthreads();
    // S = Q K^T  (16 q x 64 kv per wave)
    f32x4 sacc[4];
#pragma unroll
    for (int n = 0; n < 4; ++n) {
      sacc[n] = f32x4{0.f, 0.f, 0.f, 0.f};
#pragma unroll
      for (int f = 0; f < 4; ++f) {
        bf16x8 bk = *reinterpret_cast<bf16x8*>(&kl[(n * 16 + lr) * 136 + f * 32 + lk * 8]);
        sacc[n] = __builtin_amdgcn_mfma_f32_16x16x32_bf16(aq[f], bk, sacc[n], 0, 0, 0);
      }
      sacc[n] *= scale;
    }
    if (kv0 + 63 > hist + q0) {  // causal mask needed on this tile
#pragma unroll
      for (int n = 0; n < 4; ++n) {
        int kvi = kv0 + n * 16 + lr;
#pragma unroll
        for (int r = 0; r < 4; ++r)
          if (kvi > qposw + r) sacc[n][r] = -1e30f;
      }
    }
    // online softmax per row (rows live on 16-lane groups)
#pragma unroll
    for (int r = 0; r < 4; ++r) {
      float mx = fmaxf(fmaxf(sacc[0][r], sacc[1][r]), fmaxf(sacc[2][r], sacc[3][r]));
      mx = fmaxf(mx, __shfl_xor(mx, 1));
      mx = fmaxf(mx, __shfl_xor(mx, 2));
      mx = fmaxf(mx, __shfl_xor(mx, 4));
      mx = fmaxf(mx, __shfl_xor(mx, 8));
      float mn = fmaxf(mrow[r], mx);
      float alpha = expf(mrow[r] - mn);
      float rs = 0.f;
#pragma unroll
      for (int n = 0; n < 4; ++n) {
        float p = expf(sacc[n][r] - mn);
        sacc[n][r] = p;
        rs += p;
      }
      rs += __shfl_xor(rs, 1);
      rs += __shfl_xor(rs, 2);
      rs += __shfl_xor(rs, 4);
      rs += __shfl_xor(rs, 8);
      lsum[r] = lsum[r] * alpha + rs;
      mrow[r] = mn;
#pragma unroll
      for (int dn = 0; dn < 8; ++dn) o[dn][r] *= alpha;
    }
    // P -> LDS (per-wave region), then PV
    unsigned short* pw = &pl[w * 16 * 72];
#pragma unroll
    for (int n = 0; n < 4; ++n)
#pragma unroll
      for (int r = 0; r < 4; ++r)
        pw[(lk * 4 + r) * 72 + n * 16 + lr] = f2bf(sacc[n][r]);
    asm volatile("s_waitcnt lgkmcnt(0)" ::: "memory");
#pragma unroll
    for (int kc = 0; kc < 2; ++kc) {
      bf16x8 pa = *reinterpret_cast<bf16x8*>(&pw[lr * 72 + kc * 32 + lk * 8]);
#pragma unroll
      for (int dn = 0; dn < 8; ++dn) {
        bf16x8 bv = *reinterpret_cast<bf16x8*>(&vt[(dn * 16 + lr) * 72 + kc * 32 + lk * 8]);
        o[dn] = __builtin_amdgcn_mfma_f32_16x16x32_bf16(pa, bv, o[dn], 0, 0, 0);
      }
    }
  }
  // epilogue: out[t, h*128 + d] bf16
#pragma unroll
  for (int dn = 0; dn < 8; ++dn)
#pragma unroll
    for (int r = 0; r < 4; ++r) {
      int q = q0 + w * 16 + lk * 4 + r;
      int col = h * D_ + dn * 16 + lr;
      outb[(size_t)(b * Q_ + q) * (NH_ * D_) + col] = f2bf(o[dn][r] / lsum[r]);
    }
}

extern "C" void kernel_launch(void* const* d_in, const int* in_sizes, int n_in,
                              void* d_out, int out_size, void* d_ws, size_t ws_size,
                              hipStream_t stream) {
  const float* hidden = (const float*)d_in[0];
  const float* qkvw   = (const float*)d_in[1];
  const float* densew = (const float*)d_in[2];
  const float* pk     = (const float*)d_in[3];
  const float* pv     = (const float*)d_in[4];
  const int* histL    = (const int*)d_in[7];
  const int* bo       = (const int*)d_in[8];
  const int* posids   = (const int*)d_in[9];
  float* out = (float*)d_out;

  char* ws = (char*)d_ws;
  unsigned short* ws_hidden = (unsigned short*)(ws);                    // 33554432 B
  unsigned short* ws_w      = (unsigned short*)(ws + 33554432);         // 35651584 B
  unsigned short* ws_fused  = (unsigned short*)(ws + 69206016);         // 35651584 B
  unsigned short* ws_q      = (unsigned short*)(ws + 104857600);        // 33554432 B
  unsigned short* ws_k      = (unsigned short*)(ws + 138412032);        // 4194304 B
  unsigned short* ws_v      = (unsigned short*)(ws + 142606336);        // 4194304 B
  unsigned short* ws_attn   = ws_hidden;                                // reuse after GEMM1

  k_conv<<<2048, 256, 0, stream>>>(hidden, ws_hidden, T_ * HID_ / 4);
  k_conv<<<2048, 256, 0, stream>>>(qkvw, ws_w, QKVN * HID_ / 4);
  dim3 g1(QKVN / 128, T_ / 128);
  k_gemm_bt<<<g1, 256, 0, stream>>>(ws_hidden, ws_w, nullptr, ws_fused, T_, QKVN, HID_, QKVN);
  k_rope<<<T_, 128, 0, stream>>>(ws_fused, posids, ws_q, ws_k, ws_v);
  k_gather<<<1536, 256, 0, stream>>>(pk, pv, bo, ws_k, ws_v);
  dim3 ga(Q_ / 64, NH_, B_);
  k_attn<<<ga, 256, 0, stream>>>(ws_q, ws_k, ws_v, histL, ws_attn);
  k_conv<<<2048, 256, 0, stream>>>(densew, ws_w, HID_ * HID_ / 4);
  dim3 g2(HID_ / 128, T_ / 128);
  k_gemm_bt<<<g2, 256, 0, stream>>>(ws_attn, ws_w, out, nullptr, T_, HID_, HID_, HID_);
}

// Round 2
// 833.179 us; speedup vs baseline: 1.4046x; 1.4046x over previous
//
#include <hip/hip_runtime.h>

typedef __attribute__((ext_vector_type(8))) short bf16x8;
typedef __attribute__((ext_vector_type(4))) float f32x4;

constexpr int B_ = 8, Q_ = 512, HIST_ = 1536, HID_ = 4096, NH_ = 32, D_ = 128;
constexpr int BS_ = 64, NBLK_ = 32;
constexpr int T_ = B_ * Q_;            // 4096
constexpr int QKVN = (NH_ + 2) * D_;   // 4352
constexpr int KVC = NBLK_ * BS_;       // 2048

__device__ __forceinline__ unsigned short f2bf(float f) {
  union { float f; unsigned u; } v; v.f = f;
  unsigned r = v.u + 0x7FFFu + ((v.u >> 16) & 1u);
  return (unsigned short)(r >> 16);
}
__device__ __forceinline__ float bf2f(unsigned short s) {
  union { unsigned u; float f; } v; v.u = ((unsigned)s) << 16;
  return v.f;
}

// ---------------- f32 -> bf16 conversion (vectorized) ----------------
__global__ void k_conv(const float* __restrict__ in, unsigned short* __restrict__ out, int n4) {
  int i = blockIdx.x * blockDim.x + threadIdx.x;
  int stride = gridDim.x * blockDim.x;
  for (; i < n4; i += stride) {
    float4 v = reinterpret_cast<const float4*>(in)[i];
    ushort4 o;
    o.x = f2bf(v.x); o.y = f2bf(v.y); o.z = f2bf(v.z); o.w = f2bf(v.w);
    reinterpret_cast<ushort4*>(out)[i] = o;
  }
}

// ---------------- bf16 GEMM (m97 structure: global_load_lds + linear LDS) ----------------
// C[i,j] = sum_k A[i,k]*B[j,k]; 128x128 tile, BK=64, 4 waves (2x2), 16x16x32 MFMA.
__global__ void k_gemm_bt(const unsigned short* __restrict__ A,
                          const unsigned short* __restrict__ Bm,
                          float* __restrict__ Cf, unsigned short* __restrict__ Cb,
                          int M, int N, int K, int ldc) {
  __shared__ alignas(16) unsigned short lA[128 * 64];
  __shared__ alignas(16) unsigned short lB[128 * 64];
  const int tid = threadIdx.x;
  const int lane = tid & 63;
  const int w = tid >> 6;
  const int wr = w >> 1, wc = w & 1;
  const int n0 = blockIdx.x * 128, m0 = blockIdx.y * 128;
  const int lr = lane & 15, lk = lane >> 4;
  const int srow = lane >> 3;       // 0..7 within 8-row segment
  const int scol = (lane & 7) * 8;  // k-offset (8 bf16 = 16B)

  f32x4 acc[4][4];
#pragma unroll
  for (int m = 0; m < 4; ++m)
#pragma unroll
    for (int n = 0; n < 4; ++n) acc[m][n] = f32x4{0.f, 0.f, 0.f, 0.f};

  for (int k0 = 0; k0 < K; k0 += 64) {
#pragma unroll
    for (int i = 0; i < 4; ++i) {
      int seg = w * 4 + i;  // 0..15, each = 8 rows x 64 k = 1024 B
      const unsigned short* ga = A + (size_t)(m0 + seg * 8 + srow) * K + k0 + scol;
      const unsigned short* gb = Bm + (size_t)(n0 + seg * 8 + srow) * K + k0 + scol;
      __builtin_amdgcn_global_load_lds((const __attribute__((address_space(1))) void*)ga,
                                       (__attribute__((address_space(3))) void*)(&lA[seg * 512]), 16, 0, 0);
      __builtin_amdgcn_global_load_lds((const __attribute__((address_space(1))) void*)gb,
                                       (__attribute__((address_space(3))) void*)(&lB[seg * 512]), 16, 0, 0);
    }
    __syncthreads();
#pragma unroll
    for (int kk = 0; kk < 2; ++kk) {
      bf16x8 af[4], bfr[4];
      const int sl = (kk * 4 + lk) * 8;
#pragma unroll
      for (int m = 0; m < 4; ++m)
        af[m] = *reinterpret_cast<bf16x8*>(&lA[(wr * 64 + m * 16 + lr) * 64 + sl]);
#pragma unroll
      for (int n = 0; n < 4; ++n)
        bfr[n] = *reinterpret_cast<bf16x8*>(&lB[(wc * 64 + n * 16 + lr) * 64 + sl]);
#pragma unroll
      for (int m = 0; m < 4; ++m)
#pragma unroll
        for (int n = 0; n < 4; ++n)
          acc[m][n] = __builtin_amdgcn_mfma_f32_16x16x32_bf16(af[m], bfr[n], acc[m][n], 0, 0, 0);
    }
    __syncthreads();
  }
#pragma unroll
  for (int m = 0; m < 4; ++m)
#pragma unroll
    for (int n = 0; n < 4; ++n)
#pragma unroll
      for (int j = 0; j < 4; ++j) {
        int r = m0 + wr * 64 + m * 16 + lk * 4 + j;
        int c = n0 + wc * 64 + n * 16 + lr;
        if (Cb) Cb[(size_t)r * ldc + c] = f2bf(acc[m][n][j]);
        else Cf[(size_t)r * ldc + c] = acc[m][n][j];
      }
}

// ---------------- RoPE + repack: fused(T,4352) -> q (pre-scaled), kseq[b,kv,d], vtg[b,d,kv] ----------------
__global__ void k_rope(const unsigned short* __restrict__ fused,
                       const int* __restrict__ pos_ids,
                       unsigned short* __restrict__ qb,
                       unsigned short* __restrict__ kseq,
                       unsigned short* __restrict__ vtg) {
  int t = blockIdx.x;
  int d = threadIdx.x;  // 128 threads
  int b = t >> 9, q = t & 511;
  int pos = pos_ids[t];
  __shared__ float cs[64], sn[64];
  if (d < 64) {
    float inv = powf(10000.f, -(float)d * (1.f / 64.f));
    float ang = (float)pos * inv;
    cs[d] = cosf(ang);
    sn[d] = sinf(ang);
  }
  __syncthreads();
  const float scale = 0.08838834764831845f;  // 1/sqrt(128), folded into Q
  float c = cs[d & 63], s = sn[d & 63];
  const unsigned short* row = fused + (size_t)t * QKVN;
#pragma unroll 4
  for (int h = 0; h < NH_; ++h) {
    float x = bf2f(row[h * D_ + d]);
    float xr = (d < 64) ? -bf2f(row[h * D_ + d + 64]) : bf2f(row[h * D_ + d - 64]);
    qb[(((size_t)(b * NH_ + h)) * Q_ + q) * D_ + d] = f2bf((x * c + xr * s) * scale);
  }
  {
    float x = bf2f(row[NH_ * D_ + d]);
    float xr = (d < 64) ? -bf2f(row[NH_ * D_ + d + 64]) : bf2f(row[NH_ * D_ + d - 64]);
    kseq[((size_t)b * KVC + pos) * D_ + d] = f2bf(x * c + xr * s);
  }
  vtg[((size_t)b * D_ + d) * KVC + pos] = row[(NH_ + 1) * D_ + d];
}

// ---------------- gather history KV: paged f32 cache -> kseq (row-major) + vtg (transposed) ----------------
__global__ void k_gather(const float* __restrict__ pk, const float* __restrict__ pv,
                         const int* __restrict__ bo,
                         unsigned short* __restrict__ kseq, unsigned short* __restrict__ vtg) {
  __shared__ unsigned short vl[64 * 140];
  const int ptile = blockIdx.x;              // B_ * (HIST_/64) = 192
  const int b = ptile / (HIST_ / 64);
  const int p0 = (ptile % (HIST_ / 64)) * 64;
  const int tid = threadIdx.x;
  const int blk = bo[b * NBLK_ + (p0 >> 6)];
#pragma unroll
  for (int c = 0; c < 8; ++c) {
    int u = c * 256 + tid;  // 64 p x 32 d4
    int p = u >> 5, d4 = u & 31;
    size_t src = ((size_t)blk * BS_ + p) * D_ + d4 * 4;
    float4 kv = *reinterpret_cast<const float4*>(pk + src);
    ushort4 ko;
    ko.x = f2bf(kv.x); ko.y = f2bf(kv.y); ko.z = f2bf(kv.z); ko.w = f2bf(kv.w);
    *reinterpret_cast<ushort4*>(kseq + ((size_t)b * KVC + p0 + p) * D_ + d4 * 4) = ko;
    float4 vv = *reinterpret_cast<const float4*>(pv + src);
    ushort4 vo;
    vo.x = f2bf(vv.x); vo.y = f2bf(vv.y); vo.z = f2bf(vv.z); vo.w = f2bf(vv.w);
    *reinterpret_cast<ushort4*>(&vl[p * 140 + d4 * 4]) = vo;
  }
  __syncthreads();
#pragma unroll
  for (int c = 0; c < 4; ++c) {
    int u = c * 256 + tid;  // 128 d x 8 pg
    int d = u >> 3, pg = u & 7;
    bf16x8 vv8;
#pragma unroll
    for (int i = 0; i < 8; ++i) vv8[i] = (short)vl[(pg * 8 + i) * 140 + d];
    *reinterpret_cast<bf16x8*>(vtg + ((size_t)b * D_ + d) * KVC + p0 + pg * 8) = vv8;
  }
}

// ---------------- MQA flash attention ----------------
// block: 256 thr (4 waves). Block = (64 q rows) x (2 heads); wave = 32 q rows of one head.
// K staged [64 kv][128 d] XOR-swizzled; V^T staged [128 d][64 kv] XOR-swizzled.
__global__ __launch_bounds__(256) void k_attn(const unsigned short* __restrict__ qb,
                       const unsigned short* __restrict__ kseq,
                       const unsigned short* __restrict__ vtg,
                       const int* __restrict__ histL,
                       unsigned short* __restrict__ outb) {
  __shared__ alignas(16) unsigned short kl[64 * 128];
  __shared__ alignas(16) unsigned short vt[128 * 64];
  __shared__ alignas(16) unsigned short pl[4][32 * 72];
  const int qt = blockIdx.x, hp = blockIdx.y, b = blockIdx.z;
  const int tid = threadIdx.x, lane = tid & 63, w = tid >> 6;
  const int lr = lane & 15, lk = lane >> 4;
  const int h = hp * 2 + (w >> 1);
  const int qw = (w & 1) * 32;
  const int q0 = qt * 64;
  const int hist = histL[b];

  // Q fragments: wave owns rows q0+qw .. +31 of head h (Q pre-scaled by 1/sqrt(d))
  bf16x8 aq[2][4];
#pragma unroll
  for (int m = 0; m < 2; ++m) {
    const unsigned short* qbase = qb + (((size_t)(b * NH_ + h)) * Q_ + q0 + qw + m * 16 + lr) * D_;
#pragma unroll
    for (int f = 0; f < 4; ++f)
      aq[m][f] = *reinterpret_cast<const bf16x8*>(qbase + f * 32 + lk * 8);
  }

  f32x4 o[2][8];
#pragma unroll
  for (int m = 0; m < 2; ++m)
#pragma unroll
    for (int dn = 0; dn < 8; ++dn) o[m][dn] = f32x4{0.f, 0.f, 0.f, 0.f};
  float mrow[2][4], lsum[2][4];
#pragma unroll
  for (int m = 0; m < 2; ++m)
#pragma unroll
    for (int r = 0; r < 4; ++r) { mrow[m][r] = -1e30f; lsum[m][r] = 0.f; }

  const int ntiles = (hist + q0 + 64) >> 6;

  for (int it = 0; it < ntiles; ++it) {
    const int kv0 = it * 64;
    __syncthreads();
    // stage K tile: 64 rows x 16 slots of 16B, swizzle slot ^= row&15
#pragma unroll
    for (int c = 0; c < 4; ++c) {
      int u = c * 256 + tid;
      int row = u >> 4, s = u & 15;
      bf16x8 kvv = *reinterpret_cast<const bf16x8*>(kseq + ((size_t)b * KVC + kv0 + row) * D_ + s * 8);
      *reinterpret_cast<bf16x8*>(&kl[row * 128 + ((s ^ (row & 15)) << 3)]) = kvv;
    }
    // stage V^T tile: 128 rows x 8 slots of 16B, swizzle slot ^= row&7
#pragma unroll
    for (int c = 0; c < 4; ++c) {
      int u = c * 256 + tid;
      int row = u >> 3, s = u & 7;
      bf16x8 vv = *reinterpret_cast<const bf16x8*>(vtg + ((size_t)b * D_ + row) * KVC + kv0 + s * 8);
      *reinterpret_cast<bf16x8*>(&vt[row * 64 + ((s ^ (row & 7)) << 3)]) = vv;
    }
    __syncthreads();
    // S = Q K^T : 32 q x 64 kv per wave
    f32x4 sacc[2][4];
#pragma unroll
    for (int n = 0; n < 4; ++n) {
      sacc[0][n] = f32x4{0.f, 0.f, 0.f, 0.f};
      sacc[1][n] = f32x4{0.f, 0.f, 0.f, 0.f};
#pragma unroll
      for (int f = 0; f < 4; ++f) {
        bf16x8 bk = *reinterpret_cast<bf16x8*>(&kl[(n * 16 + lr) * 128 + (((f * 4 + lk) ^ lr) << 3)]);
        sacc[0][n] = __builtin_amdgcn_mfma_f32_16x16x32_bf16(aq[0][f], bk, sacc[0][n], 0, 0, 0);
        sacc[1][n] = __builtin_amdgcn_mfma_f32_16x16x32_bf16(aq[1][f], bk, sacc[1][n], 0, 0, 0);
      }
    }
    if (kv0 + 63 > hist + q0 + qw) {  // causal mask
#pragma unroll
      for (int m = 0; m < 2; ++m) {
        int qpos = hist + q0 + qw + m * 16 + lk * 4;
#pragma unroll
        for (int n = 0; n < 4; ++n) {
          int kvi = kv0 + n * 16 + lr;
#pragma unroll
          for (int r = 0; r < 4; ++r)
            if (kvi > qpos + r) sacc[m][n][r] = -1e30f;
        }
      }
    }
    // online softmax (rows live across 16 lanes of same lk group)
#pragma unroll
    for (int m = 0; m < 2; ++m)
#pragma unroll
      for (int r = 0; r < 4; ++r) {
        float mx = fmaxf(fmaxf(sacc[m][0][r], sacc[m][1][r]), fmaxf(sacc[m][2][r], sacc[m][3][r]));
        mx = fmaxf(mx, __shfl_xor(mx, 1));
        mx = fmaxf(mx, __shfl_xor(mx, 2));
        mx = fmaxf(mx, __shfl_xor(mx, 4));
        mx = fmaxf(mx, __shfl_xor(mx, 8));
        float mn = fmaxf(mrow[m][r], mx);
        float alpha = __expf(mrow[m][r] - mn);
        mrow[m][r] = mn;
        float rs = 0.f;
#pragma unroll
        for (int n = 0; n < 4; ++n) {
          float p = __expf(sacc[m][n][r] - mn);
          sacc[m][n][r] = p;
          rs += p;
        }
        rs += __shfl_xor(rs, 1);
        rs += __shfl_xor(rs, 2);
        rs += __shfl_xor(rs, 4);
        rs += __shfl_xor(rs, 8);
        lsum[m][r] = lsum[m][r] * alpha + rs;
#pragma unroll
        for (int dn = 0; dn < 8; ++dn) o[m][dn][r] *= alpha;
      }
    // P -> per-wave LDS (pad 72), then PV
    unsigned short* pw = pl[w];
#pragma unroll
    for (int m = 0; m < 2; ++m)
#pragma unroll
      for (int n = 0; n < 4; ++n)
#pragma unroll
        for (int r = 0; r < 4; ++r)
          pw[(m * 16 + lk * 4 + r) * 72 + n * 16 + lr] = f2bf(sacc[m][n][r]);
#pragma unroll
    for (int kc = 0; kc < 2; ++kc) {
      bf16x8 pa0 = *reinterpret_cast<bf16x8*>(&pw[(0 * 16 + lr) * 72 + kc * 32 + lk * 8]);
      bf16x8 pa1 = *reinterpret_cast<bf16x8*>(&pw[(1 * 16 + lr) * 72 + kc * 32 + lk * 8]);
#pragma unroll
      for (int dn = 0; dn < 8; ++dn) {
        bf16x8 bv = *reinterpret_cast<bf16x8*>(&vt[(dn * 16 + lr) * 64 + (((kc * 4 + lk) ^ (lr & 7)) << 3)]);
        o[0][dn] = __builtin_amdgcn_mfma_f32_16x16x32_bf16(pa0, bv, o[0][dn], 0, 0, 0);
        o[1][dn] = __builtin_amdgcn_mfma_f32_16x16x32_bf16(pa1, bv, o[1][dn], 0, 0, 0);
      }
    }
  }
  // epilogue
#pragma unroll
  for (int m = 0; m < 2; ++m)
#pragma unroll
    for (int r = 0; r < 4; ++r) {
      float il = 1.f / lsum[m][r];
      int q = q0 + qw + m * 16 + lk * 4 + r;
#pragma unroll
      for (int dn = 0; dn < 8; ++dn) {
        int col = h * D_ + dn * 16 + lr;
        outb[(size_t)(b * Q_ + q) * (NH_ * D_) + col] = f2bf(o[m][dn][r] * il);
      }
    }
}

extern "C" void kernel_launch(void* const* d_in, const int* in_sizes, int n_in,
                              void* d_out, int out_size, void* d_ws, size_t ws_size,
                              hipStream_t stream) {
  const float* hidden = (const float*)d_in[0];
  const float* qkvw   = (const float*)d_in[1];
  const float* densew = (const float*)d_in[2];
  const float* pk     = (const float*)d_in[3];
  const float* pv     = (const float*)d_in[4];
  const int* histL    = (const int*)d_in[7];
  const int* bo       = (const int*)d_in[8];
  const int* posids   = (const int*)d_in[9];
  float* out = (float*)d_out;

  char* ws = (char*)d_ws;
  unsigned short* ws_hidden = (unsigned short*)(ws);                    // 33.5 MB
  unsigned short* ws_w      = (unsigned short*)(ws + 33554432);         // 35.7 MB
  unsigned short* ws_fused  = (unsigned short*)(ws + 69206016);         // 35.7 MB
  unsigned short* ws_q      = (unsigned short*)(ws + 104857600);        // 33.5 MB
  unsigned short* ws_k      = (unsigned short*)(ws + 138412032);        // 4.2 MB
  unsigned short* ws_vt     = (unsigned short*)(ws + 142606336);        // 4.2 MB (transposed V)
  unsigned short* ws_attn   = ws_hidden;                                // reuse after GEMM1

  k_conv<<<2048, 256, 0, stream>>>(hidden, ws_hidden, T_ * HID_ / 4);
  k_conv<<<2048, 256, 0, stream>>>(qkvw, ws_w, QKVN * HID_ / 4);
  dim3 g1(QKVN / 128, T_ / 128);
  k_gemm_bt<<<g1, 256, 0, stream>>>(ws_hidden, ws_w, nullptr, ws_fused, T_, QKVN, HID_, QKVN);
  k_rope<<<T_, 128, 0, stream>>>(ws_fused, posids, ws_q, ws_k, ws_vt);
  k_gather<<<B_ * (HIST_ / 64), 256, 0, stream>>>(pk, pv, bo, ws_k, ws_vt);
  dim3 ga(Q_ / 64, NH_ / 2, B_);
  k_attn<<<ga, 256, 0, stream>>>(ws_q, ws_k, ws_vt, histL, ws_attn);
  k_conv<<<2048, 256, 0, stream>>>(densew, ws_w, HID_ * HID_ / 4);
  dim3 g2(HID_ / 128, T_ / 128);
  k_gemm_bt<<<g2, 256, 0, stream>>>(ws_attn, ws_w, out, nullptr, T_, HID_, HID_, HID_);
}

// Round 3
// 600.802 us; speedup vs baseline: 1.9478x; 1.3868x over previous
//
#include <hip/hip_runtime.h>

typedef __attribute__((ext_vector_type(8))) short bf16x8;
typedef __attribute__((ext_vector_type(4))) float f32x4;
typedef __attribute__((ext_vector_type(16))) float f32x16;
typedef __attribute__((ext_vector_type(2))) unsigned int u32x2;

constexpr int B_ = 8, Q_ = 512, HIST_ = 1536, HID_ = 4096, NH_ = 32, D_ = 128;
constexpr int BS_ = 64, NBLK_ = 32;
constexpr int T_ = B_ * Q_;            // 4096
constexpr int QKVN = (NH_ + 2) * D_;   // 4352
constexpr int KVC = NBLK_ * BS_;       // 2048

__device__ __forceinline__ unsigned short f2bf(float f) {
  union { float f; unsigned u; } v; v.f = f;
  unsigned r = v.u + 0x7FFFu + ((v.u >> 16) & 1u);
  return (unsigned short)(r >> 16);
}
__device__ __forceinline__ float bf2f(unsigned short s) {
  union { unsigned u; float f; } v; v.u = ((unsigned)s) << 16;
  return v.f;
}
__device__ __forceinline__ int cvtpk_bf16(float lo, float hi) {
  int r;
  asm("v_cvt_pk_bf16_f32 %0, %1, %2" : "=v"(r) : "v"(lo), "v"(hi));
  return r;
}

// ---------------- f32 -> bf16 conversion (vectorized) ----------------
__global__ void k_conv(const float* __restrict__ in, unsigned short* __restrict__ out, int n4) {
  int i = blockIdx.x * blockDim.x + threadIdx.x;
  int stride = gridDim.x * blockDim.x;
  for (; i < n4; i += stride) {
    float4 v = reinterpret_cast<const float4*>(in)[i];
    ushort4 o;
    o.x = f2bf(v.x); o.y = f2bf(v.y); o.z = f2bf(v.z); o.w = f2bf(v.w);
    reinterpret_cast<ushort4*>(out)[i] = o;
  }
}

// ---------------- bf16 GEMM (m97 structure: global_load_lds + linear LDS) ----------------
__global__ void k_gemm_bt(const unsigned short* __restrict__ A,
                          const unsigned short* __restrict__ Bm,
                          float* __restrict__ Cf, unsigned short* __restrict__ Cb,
                          int M, int N, int K, int ldc) {
  __shared__ alignas(16) unsigned short lA[128 * 64];
  __shared__ alignas(16) unsigned short lB[128 * 64];
  const int tid = threadIdx.x;
  const int lane = tid & 63;
  const int w = tid >> 6;
  const int wr = w >> 1, wc = w & 1;
  const int n0 = blockIdx.x * 128, m0 = blockIdx.y * 128;
  const int lr = lane & 15, lk = lane >> 4;
  const int srow = lane >> 3;
  const int scol = (lane & 7) * 8;

  f32x4 acc[4][4];
#pragma unroll
  for (int m = 0; m < 4; ++m)
#pragma unroll
    for (int n = 0; n < 4; ++n) acc[m][n] = f32x4{0.f, 0.f, 0.f, 0.f};

  for (int k0 = 0; k0 < K; k0 += 64) {
#pragma unroll
    for (int i = 0; i < 4; ++i) {
      int seg = w * 4 + i;
      const unsigned short* ga = A + (size_t)(m0 + seg * 8 + srow) * K + k0 + scol;
      const unsigned short* gb = Bm + (size_t)(n0 + seg * 8 + srow) * K + k0 + scol;
      __builtin_amdgcn_global_load_lds((const __attribute__((address_space(1))) void*)ga,
                                       (__attribute__((address_space(3))) void*)(&lA[seg * 512]), 16, 0, 0);
      __builtin_amdgcn_global_load_lds((const __attribute__((address_space(1))) void*)gb,
                                       (__attribute__((address_space(3))) void*)(&lB[seg * 512]), 16, 0, 0);
    }
    __syncthreads();
#pragma unroll
    for (int kk = 0; kk < 2; ++kk) {
      bf16x8 af[4], bfr[4];
      const int sl = (kk * 4 + lk) * 8;
#pragma unroll
      for (int m = 0; m < 4; ++m)
        af[m] = *reinterpret_cast<bf16x8*>(&lA[(wr * 64 + m * 16 + lr) * 64 + sl]);
#pragma unroll
      for (int n = 0; n < 4; ++n)
        bfr[n] = *reinterpret_cast<bf16x8*>(&lB[(wc * 64 + n * 16 + lr) * 64 + sl]);
#pragma unroll
      for (int m = 0; m < 4; ++m)
#pragma unroll
        for (int n = 0; n < 4; ++n)
          acc[m][n] = __builtin_amdgcn_mfma_f32_16x16x32_bf16(af[m], bfr[n], acc[m][n], 0, 0, 0);
    }
    __syncthreads();
  }
#pragma unroll
  for (int m = 0; m < 4; ++m)
#pragma unroll
    for (int n = 0; n < 4; ++n)
#pragma unroll
      for (int j = 0; j < 4; ++j) {
        int r = m0 + wr * 64 + m * 16 + lk * 4 + j;
        int c = n0 + wc * 64 + n * 16 + lr;
        if (Cb) Cb[(size_t)r * ldc + c] = f2bf(acc[m][n][j]);
        else Cf[(size_t)r * ldc + c] = acc[m][n][j];
      }
}

// ---------------- RoPE + repack: fused(T,4352) -> q (pre-scaled by log2e/sqrt(d)), kseq[b,kv,d], vtg[b,d,kv] ----------------
__global__ void k_rope(const unsigned short* __restrict__ fused,
                       const int* __restrict__ pos_ids,
                       unsigned short* __restrict__ qb,
                       unsigned short* __restrict__ kseq,
                       unsigned short* __restrict__ vtg) {
  int t = blockIdx.x;
  int d = threadIdx.x;  // 128 threads
  int b = t >> 9, q = t & 511;
  int pos = pos_ids[t];
  __shared__ float cs[64], sn[64];
  if (d < 64) {
    float inv = powf(10000.f, -(float)d * (1.f / 64.f));
    float ang = (float)pos * inv;
    cs[d] = cosf(ang);
    sn[d] = sinf(ang);
  }
  __syncthreads();
  // 1/sqrt(128) * log2(e): attention uses exp2
  const float scale = 0.1275174313836907f;
  float c = cs[d & 63], s = sn[d & 63];
  const unsigned short* row = fused + (size_t)t * QKVN;
#pragma unroll 4
  for (int h = 0; h < NH_; ++h) {
    float x = bf2f(row[h * D_ + d]);
    float xr = (d < 64) ? -bf2f(row[h * D_ + d + 64]) : bf2f(row[h * D_ + d - 64]);
    qb[(((size_t)(b * NH_ + h)) * Q_ + q) * D_ + d] = f2bf((x * c + xr * s) * scale);
  }
  {
    float x = bf2f(row[NH_ * D_ + d]);
    float xr = (d < 64) ? -bf2f(row[NH_ * D_ + d + 64]) : bf2f(row[NH_ * D_ + d - 64]);
    kseq[((size_t)b * KVC + pos) * D_ + d] = f2bf(x * c + xr * s);
  }
  vtg[((size_t)b * D_ + d) * KVC + pos] = row[(NH_ + 1) * D_ + d];
}

// ---------------- gather history KV: paged f32 cache -> kseq (row-major) + vtg (transposed) ----------------
__global__ void k_gather(const float* __restrict__ pk, const float* __restrict__ pv,
                         const int* __restrict__ bo,
                         unsigned short* __restrict__ kseq, unsigned short* __restrict__ vtg) {
  __shared__ unsigned short vl[64 * 140];
  const int ptile = blockIdx.x;              // B_ * (HIST_/64) = 192
  const int b = ptile / (HIST_ / 64);
  const int p0 = (ptile % (HIST_ / 64)) * 64;
  const int tid = threadIdx.x;
  const int blk = bo[b * NBLK_ + (p0 >> 6)];
#pragma unroll
  for (int c = 0; c < 8; ++c) {
    int u = c * 256 + tid;  // 64 p x 32 d4
    int p = u >> 5, d4 = u & 31;
    size_t src = ((size_t)blk * BS_ + p) * D_ + d4 * 4;
    float4 kv = *reinterpret_cast<const float4*>(pk + src);
    ushort4 ko;
    ko.x = f2bf(kv.x); ko.y = f2bf(kv.y); ko.z = f2bf(kv.z); ko.w = f2bf(kv.w);
    *reinterpret_cast<ushort4*>(kseq + ((size_t)b * KVC + p0 + p) * D_ + d4 * 4) = ko;
    float4 vv = *reinterpret_cast<const float4*>(pv + src);
    ushort4 vo;
    vo.x = f2bf(vv.x); vo.y = f2bf(vv.y); vo.z = f2bf(vv.z); vo.w = f2bf(vv.w);
    *reinterpret_cast<ushort4*>(&vl[p * 140 + d4 * 4]) = vo;
  }
  __syncthreads();
#pragma unroll
  for (int c = 0; c < 4; ++c) {
    int u = c * 256 + tid;  // 128 d x 8 pg
    int d = u >> 3, pg = u & 7;
    bf16x8 vv8;
#pragma unroll
    for (int i = 0; i < 8; ++i) vv8[i] = (short)vl[(pg * 8 + i) * 140 + d];
    *reinterpret_cast<bf16x8*>(vtg + ((size_t)b * D_ + d) * KVC + p0 + pg * 8) = vv8;
  }
}

// ---------------- MQA flash attention, 8-wave swapped-QK^T (m214/T12 structure) ----------------
// Block = 512 thr (8 waves) = 8 heads x same 32 q-rows. KVBLK=64, double-buffered LDS.
// S^T = mfma_32x32x16(K, Q): lane owns q = lane&31, kv strip in 16 regs -> in-lane softmax.
// P -> bf16 B-frag via v_cvt_pk_bf16_f32 + permlane32_swap (no LDS round-trip).
__global__ __launch_bounds__(512, 2) void k_attn(const unsigned short* __restrict__ qb,
                       const unsigned short* __restrict__ kseq,
                       const unsigned short* __restrict__ vtg,
                       const int* __restrict__ histL,
                       unsigned short* __restrict__ outb) {
  __shared__ alignas(16) unsigned short kl[2][64 * 128];  // [kv 64][d 128], slot^=(row&15)
  __shared__ alignas(16) unsigned short vt[2][128 * 64];  // [d 128][kv 64], slot^=(row&7)
  const int qt = blockIdx.x, hp = blockIdx.y, b = blockIdx.z;
  const int tid = threadIdx.x, lane = tid & 63, w = tid >> 6;
  const int H = lane >> 5, q = lane & 31;
  const int h = hp * 8 + w;
  const int q0 = qt * 32;
  const int hist = histL[b];
  const unsigned short* kseq_b = kseq + (size_t)b * KVC * D_;
  const unsigned short* vtg_b  = vtg + (size_t)b * D_ * KVC;

  // Q fragments: B-operand, col=q, k=d (pre-scaled by log2e/sqrt(d))
  const unsigned short* qrow = qb + (((size_t)(b * NH_ + h)) * Q_ + q0 + q) * D_;
  bf16x8 aq[8];
#pragma unroll
  for (int ds = 0; ds < 8; ++ds)
    aq[ds] = *reinterpret_cast<const bf16x8*>(qrow + ds * 16 + H * 8);

  f32x16 o[4];
#pragma unroll
  for (int db = 0; db < 4; ++db)
#pragma unroll
    for (int r = 0; r < 16; ++r) o[db][r] = 0.f;
  float m = -1e30f, l = 0.f;

  const int ntiles = (hist + q0 + 32 + 63) >> 6;

  auto STAGE = [&](int bufi, int kv0) {
    // K tile 16KB: LDS linear (base+lane*16), global src pre-swizzled
#pragma unroll
    for (int c = 0; c < 2; ++c) {
      int ob = c * 8192 + tid * 16;            // byte offset in K buf
      int row = ob >> 8;
      int sp = (ob >> 4) & 15;
      const unsigned short* src = kseq_b + (size_t)(kv0 + row) * D_ + (((sp ^ (row & 15)) << 3));
      __builtin_amdgcn_global_load_lds((const __attribute__((address_space(1))) void*)src,
          (__attribute__((address_space(3))) void*)(&kl[bufi][c * 4096 + w * 512]), 16, 0, 0);
    }
    // V^T tile 16KB
#pragma unroll
    for (int c = 0; c < 2; ++c) {
      int ob = c * 8192 + tid * 16;
      int row = ob >> 7;
      int sp = (ob >> 4) & 7;
      const unsigned short* src = vtg_b + (size_t)row * KVC + kv0 + (((sp ^ (row & 7)) << 3));
      __builtin_amdgcn_global_load_lds((const __attribute__((address_space(1))) void*)src,
          (__attribute__((address_space(3))) void*)(&vt[bufi][c * 4096 + w * 512]), 16, 0, 0);
    }
  };

  STAGE(0, 0);
  __syncthreads();

  for (int it = 0; it < ntiles; ++it) {
    const int cur = it & 1;
    if (it + 1 < ntiles) STAGE(cur ^ 1, (it + 1) * 64);
    const unsigned short* kb = kl[cur];
    const unsigned short* vb = vt[cur];

    // ---- S^T = K * Q^T : 2 kv-groups x 8 d-slices, 2-way split acc chains ----
    f32x16 sa = f32x16{0.f,0.f,0.f,0.f,0.f,0.f,0.f,0.f,0.f,0.f,0.f,0.f,0.f,0.f,0.f,0.f};
    f32x16 sb = sa, sc = sa, sd = sa;
#pragma unroll
    for (int ds = 0; ds < 4; ++ds) {
      const int sl = ((2 * ds + H) ^ (q & 15)) << 3;
      bf16x8 k0 = *reinterpret_cast<const bf16x8*>(kb + q * 128 + sl);
      bf16x8 k1 = *reinterpret_cast<const bf16x8*>(kb + (32 + q) * 128 + sl);
      sa = __builtin_amdgcn_mfma_f32_32x32x16_bf16(k0, aq[ds], sa, 0, 0, 0);
      sc = __builtin_amdgcn_mfma_f32_32x32x16_bf16(k1, aq[ds], sc, 0, 0, 0);
    }
#pragma unroll
    for (int ds = 4; ds < 8; ++ds) {
      const int sl = ((2 * ds + H) ^ (q & 15)) << 3;
      bf16x8 k0 = *reinterpret_cast<const bf16x8*>(kb + q * 128 + sl);
      bf16x8 k1 = *reinterpret_cast<const bf16x8*>(kb + (32 + q) * 128 + sl);
      sb = __builtin_amdgcn_mfma_f32_32x32x16_bf16(k0, aq[ds], sb, 0, 0, 0);
      sd = __builtin_amdgcn_mfma_f32_32x32x16_bf16(k1, aq[ds], sd, 0, 0, 0);
    }
    f32x16 s0 = sa + sb;   // kv = it*64 + koff + 4H
    f32x16 s1 = sc + sd;   // kv = it*64 + 32 + koff + 4H

    // ---- causal mask (last tile only) ----
    if (it == ntiles - 1) {
      const int limit = hist + q0 + q - it * 64 - 4 * H;
#pragma unroll
      for (int r = 0; r < 16; ++r) {
        const int koff = (r & 3) + 8 * ((r >> 2) & 1) + 16 * (r >> 3);
        if (koff > limit) s0[r] = -1e30f;
        if (32 + koff > limit) s1[r] = -1e30f;
      }
    }

    // ---- online softmax, in-lane (q = lane&31; halves exchange via lane^32) ----
    float pmax = s0[0];
#pragma unroll
    for (int r = 1; r < 16; ++r) pmax = fmaxf(pmax, s0[r]);
#pragma unroll
    for (int r = 0; r < 16; ++r) pmax = fmaxf(pmax, s1[r]);
    pmax = fmaxf(pmax, __shfl_xor(pmax, 32));
    if (__any(pmax > m + 11.54f)) {        // defer-max, THR = 8*log2e
      float mn = fmaxf(m, pmax);
      float al = exp2f(m - mn);
      m = mn;
      l *= al;
#pragma unroll
      for (int db = 0; db < 4; ++db)
#pragma unroll
        for (int r = 0; r < 16; ++r) o[db][r] *= al;
    }
    float rs = 0.f;
#pragma unroll
    for (int r = 0; r < 16; ++r) { s0[r] = exp2f(s0[r] - m); rs += s0[r]; }
#pragma unroll
    for (int r = 0; r < 16; ++r) { s1[r] = exp2f(s1[r] - m); rs += s1[r]; }
    rs += __shfl_xor(rs, 32);
    l += rs;

    // ---- P -> bf16 B-frags (cvt_pk + permlane32_swap), then PV ----
#pragma unroll
    for (int s = 0; s < 4; ++s) {
      float p0, p1, p2, p3, p4, p5, p6, p7;
      if (s == 0)      { p0=s0[0];p1=s0[1];p2=s0[2];p3=s0[3];p4=s0[4];p5=s0[5];p6=s0[6];p7=s0[7]; }
      else if (s == 1) { p0=s0[8];p1=s0[9];p2=s0[10];p3=s0[11];p4=s0[12];p5=s0[13];p6=s0[14];p7=s0[15]; }
      else if (s == 2) { p0=s1[0];p1=s1[1];p2=s1[2];p3=s1[3];p4=s1[4];p5=s1[5];p6=s1[6];p7=s1[7]; }
      else             { p0=s1[8];p1=s1[9];p2=s1[10];p3=s1[11];p4=s1[12];p5=s1[13];p6=s1[14];p7=s1[15]; }
      int c01 = cvtpk_bf16(p0, p1);
      int c23 = cvtpk_bf16(p2, p3);
      int c45 = cvtpk_bf16(p4, p5);
      int c67 = cvtpk_bf16(p6, p7);
      u32x2 rA = __builtin_amdgcn_permlane32_swap(c01, c45, false, false);
      u32x2 rB = __builtin_amdgcn_permlane32_swap(c23, c67, false, false);
      union { unsigned wds[4]; bf16x8 v; } uu;
      uu.wds[0] = rA[0]; uu.wds[1] = rB[0]; uu.wds[2] = rA[1]; uu.wds[3] = rB[1];
#pragma unroll
      for (int db = 0; db < 4; ++db) {
        const int row = db * 32 + q;
        bf16x8 vf = *reinterpret_cast<const bf16x8*>(vb + row * 64 + ((((2 * s + H) ^ (row & 7))) << 3));
        o[db] = __builtin_amdgcn_mfma_f32_32x32x16_bf16(vf, uu.v, o[db], 0, 0, 0);
      }
    }
    __syncthreads();
  }

  // ---- epilogue: O^T[d,q] -> out[b*Q+q0+q][h*128+d], packed 4-wide ----
  const float il = 1.f / l;
  unsigned short* orow = outb + (size_t)(b * Q_ + q0 + q) * (NH_ * D_) + h * D_;
#pragma unroll
  for (int db = 0; db < 4; ++db)
#pragma unroll
    for (int rr = 0; rr < 4; ++rr) {
      ushort4 st;
      st.x = f2bf(o[db][rr * 4 + 0] * il);
      st.y = f2bf(o[db][rr * 4 + 1] * il);
      st.z = f2bf(o[db][rr * 4 + 2] * il);
      st.w = f2bf(o[db][rr * 4 + 3] * il);
      *reinterpret_cast<ushort4*>(orow + db * 32 + rr * 8 + 4 * H) = st;
    }
}

extern "C" void kernel_launch(void* const* d_in, const int* in_sizes, int n_in,
                              void* d_out, int out_size, void* d_ws, size_t ws_size,
                              hipStream_t stream) {
  const float* hidden = (const float*)d_in[0];
  const float* qkvw   = (const float*)d_in[1];
  const float* densew = (const float*)d_in[2];
  const float* pk     = (const float*)d_in[3];
  const float* pv     = (const float*)d_in[4];
  const int* histL    = (const int*)d_in[7];
  const int* bo       = (const int*)d_in[8];
  const int* posids   = (const int*)d_in[9];
  float* out = (float*)d_out;

  char* ws = (char*)d_ws;
  unsigned short* ws_hidden = (unsigned short*)(ws);                    // 33.5 MB
  unsigned short* ws_w      = (unsigned short*)(ws + 33554432);         // 35.7 MB
  unsigned short* ws_fused  = (unsigned short*)(ws + 69206016);         // 35.7 MB
  unsigned short* ws_q      = (unsigned short*)(ws + 104857600);        // 33.5 MB
  unsigned short* ws_k      = (unsigned short*)(ws + 138412032);        // 4.2 MB
  unsigned short* ws_vt     = (unsigned short*)(ws + 142606336);        // 4.2 MB (transposed V)
  unsigned short* ws_attn   = ws_hidden;                                // reuse after GEMM1

  k_conv<<<2048, 256, 0, stream>>>(hidden, ws_hidden, T_ * HID_ / 4);
  k_conv<<<2048, 256, 0, stream>>>(qkvw, ws_w, QKVN * HID_ / 4);
  dim3 g1(QKVN / 128, T_ / 128);
  k_gemm_bt<<<g1, 256, 0, stream>>>(ws_hidden, ws_w, nullptr, ws_fused, T_, QKVN, HID_, QKVN);
  k_rope<<<T_, 128, 0, stream>>>(ws_fused, posids, ws_q, ws_k, ws_vt);
  k_gather<<<B_ * (HIST_ / 64), 256, 0, stream>>>(pk, pv, bo, ws_k, ws_vt);
  dim3 ga(Q_ / 32, NH_ / 8, B_);
  k_attn<<<ga, 512, 0, stream>>>(ws_q, ws_k, ws_vt, histL, ws_attn);
  k_conv<<<2048, 256, 0, stream>>>(densew, ws_w, HID_ * HID_ / 4);
  dim3 g2(HID_ / 128, T_ / 128);
  k_gemm_bt<<<g2, 256, 0, stream>>>(ws_attn, ws_w, out, nullptr, T_, HID_, HID_, HID_);
}

// Round 4
// 580.656 us; speedup vs baseline: 2.0154x; 1.0347x over previous
//
#include <hip/hip_runtime.h>

typedef __attribute__((ext_vector_type(8))) short bf16x8;
typedef __attribute__((ext_vector_type(4))) float f32x4;
typedef __attribute__((ext_vector_type(16))) float f32x16;
typedef __attribute__((ext_vector_type(2))) unsigned int u32x2;

constexpr int B_ = 8, Q_ = 512, HIST_ = 1536, HID_ = 4096, NH_ = 32, D_ = 128;
constexpr int BS_ = 64, NBLK_ = 32;
constexpr int T_ = B_ * Q_;            // 4096
constexpr int QKVN = (NH_ + 2) * D_;   // 4352
constexpr int KVC = NBLK_ * BS_;       // 2048

__device__ __forceinline__ unsigned short f2bf(float f) {
  union { float f; unsigned u; } v; v.f = f;
  unsigned r = v.u + 0x7FFFu + ((v.u >> 16) & 1u);
  return (unsigned short)(r >> 16);
}
__device__ __forceinline__ float bf2f(unsigned short s) {
  union { unsigned u; float f; } v; v.u = ((unsigned)s) << 16;
  return v.f;
}
__device__ __forceinline__ int cvtpk_bf16(float lo, float hi) {
  int r;
  asm("v_cvt_pk_bf16_f32 %0, %1, %2" : "=v"(r) : "v"(lo), "v"(hi));
  return r;
}

// ---------------- f32 -> bf16 conversion (vectorized) ----------------
__global__ void k_conv(const float* __restrict__ in, unsigned short* __restrict__ out, int n4) {
  int i = blockIdx.x * blockDim.x + threadIdx.x;
  int stride = gridDim.x * blockDim.x;
  for (; i < n4; i += stride) {
    float4 v = reinterpret_cast<const float4*>(in)[i];
    ushort4 o;
    o.x = f2bf(v.x); o.y = f2bf(v.y); o.z = f2bf(v.z); o.w = f2bf(v.w);
    reinterpret_cast<ushort4*>(out)[i] = o;
  }
}

// ---------------- bf16 GEMM: 256x256 tile, BK=64, 8-phase schedule (m201 template) ----------------
// C[i,j] = sum_k A[i,k]*B[j,k]. 8 waves (2M x 4N), 512 thr, 128 KiB dbuf LDS.
// Counted vmcnt(4) once per K-tile; raw s_barrier; slot^row LDS swizzle staged via
// pre-swizzled global source (global_load_lds writes linearly).
__global__ __launch_bounds__(512, 2) void k_gemm256(const unsigned short* __restrict__ A,
                          const unsigned short* __restrict__ Bm,
                          float* __restrict__ Cf, unsigned short* __restrict__ Cb,
                          int MB, int K, int ldc) {
  extern __shared__ unsigned short smem[];
  unsigned short* sA = smem;           // [buf][half][128*64]
  unsigned short* sB = smem + 32768;   // [buf][half][128*64]
  const int tid = threadIdx.x, lane = tid & 63, w = tid >> 6;
  const int wr = w >> 2, wc = w & 3;
  const int lr = lane & 15, lk = lane >> 4;

  // bijective XCD swizzle (m204)
  const int nwg = gridDim.x, orig = blockIdx.x;
  const int q8 = nwg >> 3, r8 = nwg & 7, xcd = orig & 7;
  const int wg = (xcd < r8 ? xcd * (q8 + 1) : r8 * (q8 + 1) + (xcd - r8) * q8) + (orig >> 3);
  const int m0 = (wg % MB) * 256;
  const int n0 = (wg / MB) * 256;
  const int NT = K >> 6;

  f32x4 acc[8][4];
#pragma unroll
  for (int mf = 0; mf < 8; ++mf)
#pragma unroll
    for (int nf = 0; nf < 4; ++nf) acc[mf][nf] = f32x4{0.f, 0.f, 0.f, 0.f};

  // stage one 16KB half-tile (128 rows x 64 k): linear LDS dest, inverse-swizzled global src
  auto stage = [&](const unsigned short* __restrict__ Mat, int rbase, unsigned short* regionBase,
                   int ts, int half) {
    const int di = ts < NT ? ts : NT - 1;
    const size_t k0 = (size_t)di << 6;
    char* hb = (char*)(regionBase + (ts & 1) * 16384 + half * 8192);
#pragma unroll
    for (int c = 0; c < 2; ++c) {
      const int ob = c * 8192 + (w << 10) + (lane << 4);  // byte offset in half
      const int row = ob >> 7;
      const int sl = ((ob >> 4) & 7) ^ (row & 7);
      const unsigned short* src = Mat + (size_t)(rbase + half * 128 + row) * K + k0 + sl * 8;
      __builtin_amdgcn_global_load_lds((const __attribute__((address_space(1))) void*)src,
          (__attribute__((address_space(3))) void*)(hb + c * 8192 + (w << 10)), 16, 0, 0);
    }
  };

  // prologue: tile0 full + B of tile1 (12 loads); wait tile0 (allow 4 youngest)
  stage(A, m0, sA, 0, 0); stage(A, m0, sA, 0, 1);
  stage(Bm, n0, sB, 0, 0); stage(Bm, n0, sB, 0, 1);
  stage(Bm, n0, sB, 1, 0); stage(Bm, n0, sB, 1, 1);
  asm volatile("s_waitcnt vmcnt(4)" ::: "memory");
  __builtin_amdgcn_s_barrier();

  for (int t = 0; t < NT; ++t) {
    const int cur = t & 1;
    unsigned short* a_t = sA + cur * 16384 + wr * 8192;
    unsigned short* b_t = sB + cur * 16384 + (wc >> 1) * 8192;
    bf16x8 bfr[4][2];
#pragma unroll
    for (int p = 0; p < 4; ++p) {
      bf16x8 af[2][2];
#pragma unroll
      for (int m = 0; m < 2; ++m)
#pragma unroll
        for (int kk = 0; kk < 2; ++kk) {
          const int r = p * 32 + m * 16 + lr;
          af[m][kk] = *reinterpret_cast<bf16x8*>(&a_t[r * 64 + ((((kk << 2) + lk) ^ (r & 7)) << 3)]);
        }
      if (p == 0) {
#pragma unroll
        for (int n = 0; n < 4; ++n)
#pragma unroll
          for (int kk = 0; kk < 2; ++kk) {
            const int rb = (wc & 1) * 64 + n * 16 + lr;
            bfr[n][kk] = *reinterpret_cast<bf16x8*>(&b_t[rb * 64 + ((((kk << 2) + lk) ^ (rb & 7)) << 3)]);
          }
      }
      // staging schedule: A(t+1) early, B(t+2) after B(t)'s last read (phase 0)
      if (p == 0) stage(A, m0, sA, t + 1, 0);
      if (p == 1) { stage(A, m0, sA, t + 1, 1); stage(Bm, n0, sB, t + 2, 0); }
      if (p == 2) stage(Bm, n0, sB, t + 2, 1);
      asm volatile("" ::: "memory");
      __builtin_amdgcn_s_barrier();
      asm volatile("s_waitcnt lgkmcnt(0)" ::: "memory");
      __builtin_amdgcn_sched_barrier(0);
      __builtin_amdgcn_s_setprio(1);
#pragma unroll
      for (int m = 0; m < 2; ++m)
#pragma unroll
        for (int n = 0; n < 4; ++n)
#pragma unroll
          for (int kk = 0; kk < 2; ++kk)
            acc[p * 2 + m][n] = __builtin_amdgcn_mfma_f32_16x16x32_bf16(af[m][kk], bfr[n][kk], acc[p * 2 + m][n], 0, 0, 0);
      __builtin_amdgcn_s_setprio(0);
      if (p == 3) asm volatile("s_waitcnt vmcnt(4)" ::: "memory");  // once per K-tile, never 0
      asm volatile("" ::: "memory");
      __builtin_amdgcn_s_barrier();
    }
  }
  // drain outstanding global_load_lds before workgroup can exit (LDS reuse hazard)
  asm volatile("s_waitcnt vmcnt(0)" ::: "memory");

#pragma unroll
  for (int mf = 0; mf < 8; ++mf)
#pragma unroll
    for (int nf = 0; nf < 4; ++nf)
#pragma unroll
      for (int j = 0; j < 4; ++j) {
        const int rr = m0 + wr * 128 + mf * 16 + lk * 4 + j;
        const int cc = n0 + wc * 64 + nf * 16 + lr;
        if (Cb) Cb[(size_t)rr * ldc + cc] = f2bf(acc[mf][nf][j]);
        else Cf[(size_t)rr * ldc + cc] = acc[mf][nf][j];
      }
}

// ---------------- RoPE + repack: fused(T,4352) -> q (pre-scaled by log2e/sqrt(d)), kseq[b,kv,d], vtg[b,d,kv] ----------------
__global__ void k_rope(const unsigned short* __restrict__ fused,
                       const int* __restrict__ pos_ids,
                       unsigned short* __restrict__ qb,
                       unsigned short* __restrict__ kseq,
                       unsigned short* __restrict__ vtg) {
  int t = blockIdx.x;
  int d = threadIdx.x;  // 128 threads
  int b = t >> 9, q = t & 511;
  int pos = pos_ids[t];
  __shared__ float cs[64], sn[64];
  if (d < 64) {
    float inv = powf(10000.f, -(float)d * (1.f / 64.f));
    float ang = (float)pos * inv;
    cs[d] = cosf(ang);
    sn[d] = sinf(ang);
  }
  __syncthreads();
  // 1/sqrt(128) * log2(e): attention uses exp2
  const float scale = 0.1275174313836907f;
  float c = cs[d & 63], s = sn[d & 63];
  const unsigned short* row = fused + (size_t)t * QKVN;
#pragma unroll 4
  for (int h = 0; h < NH_; ++h) {
    float x = bf2f(row[h * D_ + d]);
    float xr = (d < 64) ? -bf2f(row[h * D_ + d + 64]) : bf2f(row[h * D_ + d - 64]);
    qb[(((size_t)(b * NH_ + h)) * Q_ + q) * D_ + d] = f2bf((x * c + xr * s) * scale);
  }
  {
    float x = bf2f(row[NH_ * D_ + d]);
    float xr = (d < 64) ? -bf2f(row[NH_ * D_ + d + 64]) : bf2f(row[NH_ * D_ + d - 64]);
    kseq[((size_t)b * KVC + pos) * D_ + d] = f2bf(x * c + xr * s);
  }
  vtg[((size_t)b * D_ + d) * KVC + pos] = row[(NH_ + 1) * D_ + d];
}

// ---------------- gather history KV: paged f32 cache -> kseq (row-major) + vtg (transposed) ----------------
__global__ void k_gather(const float* __restrict__ pk, const float* __restrict__ pv,
                         const int* __restrict__ bo,
                         unsigned short* __restrict__ kseq, unsigned short* __restrict__ vtg) {
  __shared__ unsigned short vl[64 * 140];
  const int ptile = blockIdx.x;              // B_ * (HIST_/64) = 192
  const int b = ptile / (HIST_ / 64);
  const int p0 = (ptile % (HIST_ / 64)) * 64;
  const int tid = threadIdx.x;
  const int blk = bo[b * NBLK_ + (p0 >> 6)];
#pragma unroll
  for (int c = 0; c < 8; ++c) {
    int u = c * 256 + tid;  // 64 p x 32 d4
    int p = u >> 5, d4 = u & 31;
    size_t src = ((size_t)blk * BS_ + p) * D_ + d4 * 4;
    float4 kv = *reinterpret_cast<const float4*>(pk + src);
    ushort4 ko;
    ko.x = f2bf(kv.x); ko.y = f2bf(kv.y); ko.z = f2bf(kv.z); ko.w = f2bf(kv.w);
    *reinterpret_cast<ushort4*>(kseq + ((size_t)b * KVC + p0 + p) * D_ + d4 * 4) = ko;
    float4 vv = *reinterpret_cast<const float4*>(pv + src);
    ushort4 vo;
    vo.x = f2bf(vv.x); vo.y = f2bf(vv.y); vo.z = f2bf(vv.z); vo.w = f2bf(vv.w);
    *reinterpret_cast<ushort4*>(&vl[p * 140 + d4 * 4]) = vo;
  }
  __syncthreads();
#pragma unroll
  for (int c = 0; c < 4; ++c) {
    int u = c * 256 + tid;  // 128 d x 8 pg
    int d = u >> 3, pg = u & 7;
    bf16x8 vv8;
#pragma unroll
    for (int i = 0; i < 8; ++i) vv8[i] = (short)vl[(pg * 8 + i) * 140 + d];
    *reinterpret_cast<bf16x8*>(vtg + ((size_t)b * D_ + d) * KVC + p0 + pg * 8) = vv8;
  }
}

// ---------------- MQA flash attention, 8-wave swapped-QK^T (m214/T12 structure) ----------------
__global__ __launch_bounds__(512, 2) void k_attn(const unsigned short* __restrict__ qb,
                       const unsigned short* __restrict__ kseq,
                       const unsigned short* __restrict__ vtg,
                       const int* __restrict__ histL,
                       unsigned short* __restrict__ outb) {
  __shared__ alignas(16) unsigned short kl[2][64 * 128];  // [kv 64][d 128], slot^=(row&15)
  __shared__ alignas(16) unsigned short vt[2][128 * 64];  // [d 128][kv 64], slot^=(row&7)
  const int qt = blockIdx.x, hp = blockIdx.y, b = blockIdx.z;
  const int tid = threadIdx.x, lane = tid & 63, w = tid >> 6;
  const int H = lane >> 5, q = lane & 31;
  const int h = hp * 8 + w;
  const int q0 = qt * 32;
  const int hist = histL[b];
  const unsigned short* kseq_b = kseq + (size_t)b * KVC * D_;
  const unsigned short* vtg_b  = vtg + (size_t)b * D_ * KVC;

  const unsigned short* qrow = qb + (((size_t)(b * NH_ + h)) * Q_ + q0 + q) * D_;
  bf16x8 aq[8];
#pragma unroll
  for (int ds = 0; ds < 8; ++ds)
    aq[ds] = *reinterpret_cast<const bf16x8*>(qrow + ds * 16 + H * 8);

  f32x16 o[4];
#pragma unroll
  for (int db = 0; db < 4; ++db)
#pragma unroll
    for (int r = 0; r < 16; ++r) o[db][r] = 0.f;
  float m = -1e30f, l = 0.f;

  const int ntiles = (hist + q0 + 32 + 63) >> 6;

  auto STAGE = [&](int bufi, int kv0) {
#pragma unroll
    for (int c = 0; c < 2; ++c) {
      int ob = c * 8192 + tid * 16;
      int row = ob >> 8;
      int sp = (ob >> 4) & 15;
      const unsigned short* src = kseq_b + (size_t)(kv0 + row) * D_ + (((sp ^ (row & 15)) << 3));
      __builtin_amdgcn_global_load_lds((const __attribute__((address_space(1))) void*)src,
          (__attribute__((address_space(3))) void*)(&kl[bufi][c * 4096 + w * 512]), 16, 0, 0);
    }
#pragma unroll
    for (int c = 0; c < 2; ++c) {
      int ob = c * 8192 + tid * 16;
      int row = ob >> 7;
      int sp = (ob >> 4) & 7;
      const unsigned short* src = vtg_b + (size_t)row * KVC + kv0 + (((sp ^ (row & 7)) << 3));
      __builtin_amdgcn_global_load_lds((const __attribute__((address_space(1))) void*)src,
          (__attribute__((address_space(3))) void*)(&vt[bufi][c * 4096 + w * 512]), 16, 0, 0);
    }
  };

  STAGE(0, 0);
  __syncthreads();

  for (int it = 0; it < ntiles; ++it) {
    const int cur = it & 1;
    if (it + 1 < ntiles) STAGE(cur ^ 1, (it + 1) * 64);
    const unsigned short* kb = kl[cur];
    const unsigned short* vb = vt[cur];

    f32x16 sa = f32x16{0.f,0.f,0.f,0.f,0.f,0.f,0.f,0.f,0.f,0.f,0.f,0.f,0.f,0.f,0.f,0.f};
    f32x16 sb = sa, sc = sa, sd = sa;
#pragma unroll
    for (int ds = 0; ds < 4; ++ds) {
      const int sl = ((2 * ds + H) ^ (q & 15)) << 3;
      bf16x8 k0 = *reinterpret_cast<const bf16x8*>(kb + q * 128 + sl);
      bf16x8 k1 = *reinterpret_cast<const bf16x8*>(kb + (32 + q) * 128 + sl);
      sa = __builtin_amdgcn_mfma_f32_32x32x16_bf16(k0, aq[ds], sa, 0, 0, 0);
      sc = __builtin_amdgcn_mfma_f32_32x32x16_bf16(k1, aq[ds], sc, 0, 0, 0);
    }
#pragma unroll
    for (int ds = 4; ds < 8; ++ds) {
      const int sl = ((2 * ds + H) ^ (q & 15)) << 3;
      bf16x8 k0 = *reinterpret_cast<const bf16x8*>(kb + q * 128 + sl);
      bf16x8 k1 = *reinterpret_cast<const bf16x8*>(kb + (32 + q) * 128 + sl);
      sb = __builtin_amdgcn_mfma_f32_32x32x16_bf16(k0, aq[ds], sb, 0, 0, 0);
      sd = __builtin_amdgcn_mfma_f32_32x32x16_bf16(k1, aq[ds], sd, 0, 0, 0);
    }
    f32x16 s0 = sa + sb;
    f32x16 s1 = sc + sd;

    if (it == ntiles - 1) {
      const int limit = hist + q0 + q - it * 64 - 4 * H;
#pragma unroll
      for (int r = 0; r < 16; ++r) {
        const int koff = (r & 3) + 8 * ((r >> 2) & 1) + 16 * (r >> 3);
        if (koff > limit) s0[r] = -1e30f;
        if (32 + koff > limit) s1[r] = -1e30f;
      }
    }

    float pmax = s0[0];
#pragma unroll
    for (int r = 1; r < 16; ++r) pmax = fmaxf(pmax, s0[r]);
#pragma unroll
    for (int r = 0; r < 16; ++r) pmax = fmaxf(pmax, s1[r]);
    pmax = fmaxf(pmax, __shfl_xor(pmax, 32));
    if (__any(pmax > m + 11.54f)) {
      float mn = fmaxf(m, pmax);
      float al = exp2f(m - mn);
      m = mn;
      l *= al;
#pragma unroll
      for (int db = 0; db < 4; ++db)
#pragma unroll
        for (int r = 0; r < 16; ++r) o[db][r] *= al;
    }
    float rs = 0.f;
#pragma unroll
    for (int r = 0; r < 16; ++r) { s0[r] = exp2f(s0[r] - m); rs += s0[r]; }
#pragma unroll
    for (int r = 0; r < 16; ++r) { s1[r] = exp2f(s1[r] - m); rs += s1[r]; }
    rs += __shfl_xor(rs, 32);
    l += rs;

#pragma unroll
    for (int s = 0; s < 4; ++s) {
      float p0, p1, p2, p3, p4, p5, p6, p7;
      if (s == 0)      { p0=s0[0];p1=s0[1];p2=s0[2];p3=s0[3];p4=s0[4];p5=s0[5];p6=s0[6];p7=s0[7]; }
      else if (s == 1) { p0=s0[8];p1=s0[9];p2=s0[10];p3=s0[11];p4=s0[12];p5=s0[13];p6=s0[14];p7=s0[15]; }
      else if (s == 2) { p0=s1[0];p1=s1[1];p2=s1[2];p3=s1[3];p4=s1[4];p5=s1[5];p6=s1[6];p7=s1[7]; }
      else             { p0=s1[8];p1=s1[9];p2=s1[10];p3=s1[11];p4=s1[12];p5=s1[13];p6=s1[14];p7=s1[15]; }
      int c01 = cvtpk_bf16(p0, p1);
      int c23 = cvtpk_bf16(p2, p3);
      int c45 = cvtpk_bf16(p4, p5);
      int c67 = cvtpk_bf16(p6, p7);
      u32x2 rA = __builtin_amdgcn_permlane32_swap(c01, c45, false, false);
      u32x2 rB = __builtin_amdgcn_permlane32_swap(c23, c67, false, false);
      union { unsigned wds[4]; bf16x8 v; } uu;
      uu.wds[0] = rA[0]; uu.wds[1] = rB[0]; uu.wds[2] = rA[1]; uu.wds[3] = rB[1];
#pragma unroll
      for (int db = 0; db < 4; ++db) {
        const int row = db * 32 + q;
        bf16x8 vf = *reinterpret_cast<const bf16x8*>(vb + row * 64 + ((((2 * s + H) ^ (row & 7))) << 3));
        o[db] = __builtin_amdgcn_mfma_f32_32x32x16_bf16(vf, uu.v, o[db], 0, 0, 0);
      }
    }
    __syncthreads();
  }

  const float il = 1.f / l;
  unsigned short* orow = outb + (size_t)(b * Q_ + q0 + q) * (NH_ * D_) + h * D_;
#pragma unroll
  for (int db = 0; db < 4; ++db)
#pragma unroll
    for (int rr = 0; rr < 4; ++rr) {
      ushort4 st;
      st.x = f2bf(o[db][rr * 4 + 0] * il);
      st.y = f2bf(o[db][rr * 4 + 1] * il);
      st.z = f2bf(o[db][rr * 4 + 2] * il);
      st.w = f2bf(o[db][rr * 4 + 3] * il);
      *reinterpret_cast<ushort4*>(orow + db * 32 + rr * 8 + 4 * H) = st;
    }
}

extern "C" void kernel_launch(void* const* d_in, const int* in_sizes, int n_in,
                              void* d_out, int out_size, void* d_ws, size_t ws_size,
                              hipStream_t stream) {
  const float* hidden = (const float*)d_in[0];
  const float* qkvw   = (const float*)d_in[1];
  const float* densew = (const float*)d_in[2];
  const float* pk     = (const float*)d_in[3];
  const float* pv     = (const float*)d_in[4];
  const int* histL    = (const int*)d_in[7];
  const int* bo       = (const int*)d_in[8];
  const int* posids   = (const int*)d_in[9];
  float* out = (float*)d_out;

  char* ws = (char*)d_ws;
  unsigned short* ws_hidden = (unsigned short*)(ws);                    // 33.5 MB
  unsigned short* ws_w      = (unsigned short*)(ws + 33554432);         // 35.7 MB
  unsigned short* ws_fused  = (unsigned short*)(ws + 69206016);         // 35.7 MB
  unsigned short* ws_q      = (unsigned short*)(ws + 104857600);        // 33.5 MB
  unsigned short* ws_k      = (unsigned short*)(ws + 138412032);        // 4.2 MB
  unsigned short* ws_vt     = (unsigned short*)(ws + 142606336);        // 4.2 MB (transposed V)
  unsigned short* ws_attn   = ws_hidden;                                // reuse after GEMM1

  k_conv<<<2048, 256, 0, stream>>>(hidden, ws_hidden, T_ * HID_ / 4);
  k_conv<<<2048, 256, 0, stream>>>(qkvw, ws_w, QKVN * HID_ / 4);
  k_gemm256<<<dim3((T_ / 256) * (QKVN / 256)), 512, 131072, stream>>>(
      ws_hidden, ws_w, nullptr, ws_fused, T_ / 256, HID_, QKVN);
  k_rope<<<T_, 128, 0, stream>>>(ws_fused, posids, ws_q, ws_k, ws_vt);
  k_gather<<<B_ * (HIST_ / 64), 256, 0, stream>>>(pk, pv, bo, ws_k, ws_vt);
  dim3 ga(Q_ / 32, NH_ / 8, B_);
  k_attn<<<ga, 512, 0, stream>>>(ws_q, ws_k, ws_vt, histL, ws_attn);
  k_conv<<<2048, 256, 0, stream>>>(densew, ws_w, HID_ * HID_ / 4);
  k_gemm256<<<dim3((T_ / 256) * (HID_ / 256)), 512, 131072, stream>>>(
      ws_attn, ws_w, out, nullptr, T_ / 256, HID_, HID_);
}

// Round 5
// 565.616 us; speedup vs baseline: 2.0690x; 1.0266x over previous
//
#include <hip/hip_runtime.h>

typedef __attribute__((ext_vector_type(8))) short bf16x8;
typedef __attribute__((ext_vector_type(4))) float f32x4;
typedef __attribute__((ext_vector_type(16))) float f32x16;
typedef __attribute__((ext_vector_type(2))) unsigned int u32x2;

constexpr int B_ = 8, Q_ = 512, HIST_ = 1536, HID_ = 4096, NH_ = 32, D_ = 128;
constexpr int BS_ = 64, NBLK_ = 32;
constexpr int T_ = B_ * Q_;            // 4096
constexpr int QKVN = (NH_ + 2) * D_;   // 4352
constexpr int KVC = NBLK_ * BS_;       // 2048

__device__ __forceinline__ unsigned short f2bf(float f) {
  union { float f; unsigned u; } v; v.f = f;
  unsigned r = v.u + 0x7FFFu + ((v.u >> 16) & 1u);
  return (unsigned short)(r >> 16);
}
__device__ __forceinline__ float bf2f(unsigned short s) {
  union { unsigned u; float f; } v; v.u = ((unsigned)s) << 16;
  return v.f;
}
__device__ __forceinline__ int cvtpk_bf16(float lo, float hi) {
  int r;
  asm("v_cvt_pk_bf16_f32 %0, %1, %2" : "=v"(r) : "v"(lo), "v"(hi));
  return r;
}

// ---------------- f32 -> bf16 conversion (vectorized) ----------------
__global__ void k_conv(const float* __restrict__ in, unsigned short* __restrict__ out, int n4) {
  int i = blockIdx.x * blockDim.x + threadIdx.x;
  int stride = gridDim.x * blockDim.x;
  for (; i < n4; i += stride) {
    float4 v = reinterpret_cast<const float4*>(in)[i];
    ushort4 o;
    o.x = f2bf(v.x); o.y = f2bf(v.y); o.z = f2bf(v.z); o.w = f2bf(v.w);
    reinterpret_cast<ushort4*>(out)[i] = o;
  }
}

// ---------------- bf16 GEMM: 256x256, BK=64, 8-phase (2 K-tiles/iter), B-reg dbuf ----------------
// C[i,j] = sum_k A[i,k]*B[j,k]. 8 waves (2M x 4N), 512 thr, 128 KiB dbuf LDS.
// Per phase: 4 A ds_reads (+4 B-next reads at q2/q3), 1 half-tile global_load_lds,
// barrier, lgkmcnt(0), 16 MFMA, barrier. vmcnt(4) at q1 (guarantees B(t+1) before
// its q2/q3 register load) and q3 (guarantees A(t+1) before next tile's q0).
#define LDA4(af, cur_, qq)                                                              \
  {                                                                                     \
    const unsigned short* a_t = sA + (cur_) * 16384;                                    \
    const int r0 = wr * 128 + (qq) * 32 + lr;                                           \
    const int r1 = r0 + 16;                                                             \
    af[0][0] = *(const bf16x8*)&a_t[r0 * 64 + ((lk ^ (r0 & 7)) << 3)];                  \
    af[0][1] = *(const bf16x8*)&a_t[r0 * 64 + (((4 + lk) ^ (r0 & 7)) << 3)];            \
    af[1][0] = *(const bf16x8*)&a_t[r1 * 64 + ((lk ^ (r1 & 7)) << 3)];                  \
    af[1][1] = *(const bf16x8*)&a_t[r1 * 64 + (((4 + lk) ^ (r1 & 7)) << 3)];            \
  }

#define LDB2(dst, cur_, nn)                                                             \
  {                                                                                     \
    const unsigned short* b_t = sB + (cur_) * 16384;                                    \
    const int rb = wc * 64 + (nn) * 16 + lr;                                            \
    dst[nn][0] = *(const bf16x8*)&b_t[rb * 64 + ((lk ^ (rb & 7)) << 3)];                \
    dst[nn][1] = *(const bf16x8*)&b_t[rb * 64 + (((4 + lk) ^ (rb & 7)) << 3)];          \
  }

#define MFMA16(qq, af, Bf)                                                              \
  __builtin_amdgcn_s_setprio(1);                                                        \
  acc[(qq)*2+0][0] = __builtin_amdgcn_mfma_f32_16x16x32_bf16(af[0][0], Bf[0][0], acc[(qq)*2+0][0], 0, 0, 0); \
  acc[(qq)*2+0][1] = __builtin_amdgcn_mfma_f32_16x16x32_bf16(af[0][0], Bf[1][0], acc[(qq)*2+0][1], 0, 0, 0); \
  acc[(qq)*2+0][2] = __builtin_amdgcn_mfma_f32_16x16x32_bf16(af[0][0], Bf[2][0], acc[(qq)*2+0][2], 0, 0, 0); \
  acc[(qq)*2+0][3] = __builtin_amdgcn_mfma_f32_16x16x32_bf16(af[0][0], Bf[3][0], acc[(qq)*2+0][3], 0, 0, 0); \
  acc[(qq)*2+1][0] = __builtin_amdgcn_mfma_f32_16x16x32_bf16(af[1][0], Bf[0][0], acc[(qq)*2+1][0], 0, 0, 0); \
  acc[(qq)*2+1][1] = __builtin_amdgcn_mfma_f32_16x16x32_bf16(af[1][0], Bf[1][0], acc[(qq)*2+1][1], 0, 0, 0); \
  acc[(qq)*2+1][2] = __builtin_amdgcn_mfma_f32_16x16x32_bf16(af[1][0], Bf[2][0], acc[(qq)*2+1][2], 0, 0, 0); \
  acc[(qq)*2+1][3] = __builtin_amdgcn_mfma_f32_16x16x32_bf16(af[1][0], Bf[3][0], acc[(qq)*2+1][3], 0, 0, 0); \
  acc[(qq)*2+0][0] = __builtin_amdgcn_mfma_f32_16x16x32_bf16(af[0][1], Bf[0][1], acc[(qq)*2+0][0], 0, 0, 0); \
  acc[(qq)*2+0][1] = __builtin_amdgcn_mfma_f32_16x16x32_bf16(af[0][1], Bf[1][1], acc[(qq)*2+0][1], 0, 0, 0); \
  acc[(qq)*2+0][2] = __builtin_amdgcn_mfma_f32_16x16x32_bf16(af[0][1], Bf[2][1], acc[(qq)*2+0][2], 0, 0, 0); \
  acc[(qq)*2+0][3] = __builtin_amdgcn_mfma_f32_16x16x32_bf16(af[0][1], Bf[3][1], acc[(qq)*2+0][3], 0, 0, 0); \
  acc[(qq)*2+1][0] = __builtin_amdgcn_mfma_f32_16x16x32_bf16(af[1][1], Bf[0][1], acc[(qq)*2+1][0], 0, 0, 0); \
  acc[(qq)*2+1][1] = __builtin_amdgcn_mfma_f32_16x16x32_bf16(af[1][1], Bf[1][1], acc[(qq)*2+1][1], 0, 0, 0); \
  acc[(qq)*2+1][2] = __builtin_amdgcn_mfma_f32_16x16x32_bf16(af[1][1], Bf[2][1], acc[(qq)*2+1][2], 0, 0, 0); \
  acc[(qq)*2+1][3] = __builtin_amdgcn_mfma_f32_16x16x32_bf16(af[1][1], Bf[3][1], acc[(qq)*2+1][3], 0, 0, 0); \
  __builtin_amdgcn_s_setprio(0);

#define SYNC_IN                                                                         \
  asm volatile("" ::: "memory");                                                        \
  __builtin_amdgcn_s_barrier();                                                         \
  asm volatile("s_waitcnt lgkmcnt(0)" ::: "memory");                                    \
  __builtin_amdgcn_sched_barrier(0);

#define SYNC_OUT                                                                        \
  asm volatile("" ::: "memory");                                                        \
  __builtin_amdgcn_s_barrier();

#define TILE(t_, cur_, BCUR, BNEXT)                                                     \
  {                                                                                     \
    bf16x8 af[2][2];                                                                    \
    LDA4(af, cur_, 0);                                                                  \
    stage(A, m0, sA, (t_) + 1, 0);                                                      \
    SYNC_IN; MFMA16(0, af, BCUR); SYNC_OUT;                                             \
    LDA4(af, cur_, 1);                                                                  \
    stage(A, m0, sA, (t_) + 1, 1);                                                      \
    asm volatile("s_waitcnt vmcnt(4)" ::: "memory");                                    \
    SYNC_IN; MFMA16(1, af, BCUR); SYNC_OUT;                                             \
    LDA4(af, cur_, 2);                                                                  \
    LDB2(BNEXT, (cur_) ^ 1, 0); LDB2(BNEXT, (cur_) ^ 1, 1);                             \
    stage(Bm, n0, sB, (t_) + 2, 0);                                                     \
    SYNC_IN; MFMA16(2, af, BCUR); SYNC_OUT;                                             \
    LDA4(af, cur_, 3);                                                                  \
    LDB2(BNEXT, (cur_) ^ 1, 2); LDB2(BNEXT, (cur_) ^ 1, 3);                             \
    stage(Bm, n0, sB, (t_) + 2, 1);                                                     \
    asm volatile("s_waitcnt vmcnt(4)" ::: "memory");                                    \
    SYNC_IN; MFMA16(3, af, BCUR); SYNC_OUT;                                             \
  }

__global__ __launch_bounds__(512, 2) void k_gemm256(const unsigned short* __restrict__ A,
                          const unsigned short* __restrict__ Bm,
                          float* __restrict__ Cf, unsigned short* __restrict__ Cb,
                          int MB, int K, int ldc) {
  extern __shared__ unsigned short smem[];
  unsigned short* sA = smem;           // [2][256*64]
  unsigned short* sB = smem + 32768;   // [2][256*64]
  const int tid = threadIdx.x, lane = tid & 63, w = tid >> 6;
  const int wr = w >> 2, wc = w & 3;
  const int lr = lane & 15, lk = lane >> 4;

  // bijective XCD swizzle (m204)
  const int nwg = gridDim.x, orig = blockIdx.x;
  const int q8 = nwg >> 3, r8 = nwg & 7, xcd = orig & 7;
  const int wg = (xcd < r8 ? xcd * (q8 + 1) : r8 * (q8 + 1) + (xcd - r8) * q8) + (orig >> 3);
  const int m0 = (wg % MB) * 256;
  const int n0 = (wg / MB) * 256;
  const int NT = K >> 6;

  f32x4 acc[8][4];
#pragma unroll
  for (int mf = 0; mf < 8; ++mf)
#pragma unroll
    for (int nf = 0; nf < 4; ++nf) acc[mf][nf] = f32x4{0.f, 0.f, 0.f, 0.f};

  // stage one 16KB half-tile: linear LDS dest, inverse-swizzled global source
  auto stage = [&](const unsigned short* __restrict__ Mat, int rbase, unsigned short* regionBase,
                   int ts, int half) {
    const int di = ts < NT ? ts : NT - 1;
    const size_t k0 = (size_t)di << 6;
    char* hb = (char*)(regionBase + (ts & 1) * 16384 + half * 8192);
#pragma unroll
    for (int c = 0; c < 2; ++c) {
      const int ob = c * 8192 + (w << 10) + (lane << 4);  // byte offset within half
      const int row = ob >> 7;
      const int sl = ((ob >> 4) & 7) ^ (row & 7);
      const unsigned short* src = Mat + (size_t)(rbase + half * 128 + row) * K + k0 + sl * 8;
      __builtin_amdgcn_global_load_lds((const __attribute__((address_space(1))) void*)src,
          (__attribute__((address_space(3))) void*)(hb + c * 8192 + (w << 10)), 16, 0, 0);
    }
  };

  // prologue: A(0), B(0), B(1) staged; wait tile0 (leave B(1) in flight); hoist B(0)->regs
  stage(A, m0, sA, 0, 0); stage(A, m0, sA, 0, 1);
  stage(Bm, n0, sB, 0, 0); stage(Bm, n0, sB, 0, 1);
  stage(Bm, n0, sB, 1, 0); stage(Bm, n0, sB, 1, 1);
  asm volatile("s_waitcnt vmcnt(4)" ::: "memory");
  __builtin_amdgcn_s_barrier();
  bf16x8 bX[4][2], bY[4][2];
  LDB2(bX, 0, 0); LDB2(bX, 0, 1); LDB2(bX, 0, 2); LDB2(bX, 0, 3);
  // bX reads drain at tile0 q0's lgkmcnt(0)

  for (int t = 0; t < NT; t += 2) {
    TILE(t, 0, bX, bY)
    TILE(t + 1, 1, bY, bX)
  }
  asm volatile("s_waitcnt vmcnt(0)" ::: "memory");

#pragma unroll
  for (int mf = 0; mf < 8; ++mf)
#pragma unroll
    for (int nf = 0; nf < 4; ++nf)
#pragma unroll
      for (int j = 0; j < 4; ++j) {
        const int rr = m0 + wr * 128 + mf * 16 + lk * 4 + j;
        const int cc = n0 + wc * 64 + nf * 16 + lr;
        if (Cb) Cb[(size_t)rr * ldc + cc] = f2bf(acc[mf][nf][j]);
        else Cf[(size_t)rr * ldc + cc] = acc[mf][nf][j];
      }
}

// ---------------- RoPE + repack: fused(T,4352) -> q (pre-scaled by log2e/sqrt(d)), kseq[b,kv,d], vtg[b,d,kv] ----------------
__global__ void k_rope(const unsigned short* __restrict__ fused,
                       const int* __restrict__ pos_ids,
                       unsigned short* __restrict__ qb,
                       unsigned short* __restrict__ kseq,
                       unsigned short* __restrict__ vtg) {
  int t = blockIdx.x;
  int d = threadIdx.x;  // 128 threads
  int b = t >> 9, q = t & 511;
  int pos = pos_ids[t];
  __shared__ float cs[64], sn[64];
  if (d < 64) {
    float inv = powf(10000.f, -(float)d * (1.f / 64.f));
    float ang = (float)pos * inv;
    cs[d] = cosf(ang);
    sn[d] = sinf(ang);
  }
  __syncthreads();
  // 1/sqrt(128) * log2(e): attention uses exp2
  const float scale = 0.1275174313836907f;
  float c = cs[d & 63], s = sn[d & 63];
  const unsigned short* row = fused + (size_t)t * QKVN;
#pragma unroll 4
  for (int h = 0; h < NH_; ++h) {
    float x = bf2f(row[h * D_ + d]);
    float xr = (d < 64) ? -bf2f(row[h * D_ + d + 64]) : bf2f(row[h * D_ + d - 64]);
    qb[(((size_t)(b * NH_ + h)) * Q_ + q) * D_ + d] = f2bf((x * c + xr * s) * scale);
  }
  {
    float x = bf2f(row[NH_ * D_ + d]);
    float xr = (d < 64) ? -bf2f(row[NH_ * D_ + d + 64]) : bf2f(row[NH_ * D_ + d - 64]);
    kseq[((size_t)b * KVC + pos) * D_ + d] = f2bf(x * c + xr * s);
  }
  vtg[((size_t)b * D_ + d) * KVC + pos] = row[(NH_ + 1) * D_ + d];
}

// ---------------- gather history KV: paged f32 cache -> kseq (row-major) + vtg (transposed) ----------------
__global__ void k_gather(const float* __restrict__ pk, const float* __restrict__ pv,
                         const int* __restrict__ bo,
                         unsigned short* __restrict__ kseq, unsigned short* __restrict__ vtg) {
  __shared__ unsigned short vl[64 * 140];
  const int ptile = blockIdx.x;              // B_ * (HIST_/64) = 192
  const int b = ptile / (HIST_ / 64);
  const int p0 = (ptile % (HIST_ / 64)) * 64;
  const int tid = threadIdx.x;
  const int blk = bo[b * NBLK_ + (p0 >> 6)];
#pragma unroll
  for (int c = 0; c < 8; ++c) {
    int u = c * 256 + tid;  // 64 p x 32 d4
    int p = u >> 5, d4 = u & 31;
    size_t src = ((size_t)blk * BS_ + p) * D_ + d4 * 4;
    float4 kv = *reinterpret_cast<const float4*>(pk + src);
    ushort4 ko;
    ko.x = f2bf(kv.x); ko.y = f2bf(kv.y); ko.z = f2bf(kv.z); ko.w = f2bf(kv.w);
    *reinterpret_cast<ushort4*>(kseq + ((size_t)b * KVC + p0 + p) * D_ + d4 * 4) = ko;
    float4 vv = *reinterpret_cast<const float4*>(pv + src);
    ushort4 vo;
    vo.x = f2bf(vv.x); vo.y = f2bf(vv.y); vo.z = f2bf(vv.z); vo.w = f2bf(vv.w);
    *reinterpret_cast<ushort4*>(&vl[p * 140 + d4 * 4]) = vo;
  }
  __syncthreads();
#pragma unroll
  for (int c = 0; c < 4; ++c) {
    int u = c * 256 + tid;  // 128 d x 8 pg
    int d = u >> 3, pg = u & 7;
    bf16x8 vv8;
#pragma unroll
    for (int i = 0; i < 8; ++i) vv8[i] = (short)vl[(pg * 8 + i) * 140 + d];
    *reinterpret_cast<bf16x8*>(vtg + ((size_t)b * D_ + d) * KVC + p0 + pg * 8) = vv8;
  }
}

// ---------------- MQA flash attention, 8-wave swapped-QK^T (m214/T12 structure) ----------------
__global__ __launch_bounds__(512, 2) void k_attn(const unsigned short* __restrict__ qb,
                       const unsigned short* __restrict__ kseq,
                       const unsigned short* __restrict__ vtg,
                       const int* __restrict__ histL,
                       unsigned short* __restrict__ outb) {
  __shared__ alignas(16) unsigned short kl[2][64 * 128];  // [kv 64][d 128], slot^=(row&15)
  __shared__ alignas(16) unsigned short vt[2][128 * 64];  // [d 128][kv 64], slot^=(row&7)
  const int qt = blockIdx.x, hp = blockIdx.y, b = blockIdx.z;
  const int tid = threadIdx.x, lane = tid & 63, w = tid >> 6;
  const int H = lane >> 5, q = lane & 31;
  const int h = hp * 8 + w;
  const int q0 = qt * 32;
  const int hist = histL[b];
  const unsigned short* kseq_b = kseq + (size_t)b * KVC * D_;
  const unsigned short* vtg_b  = vtg + (size_t)b * D_ * KVC;

  const unsigned short* qrow = qb + (((size_t)(b * NH_ + h)) * Q_ + q0 + q) * D_;
  bf16x8 aq[8];
#pragma unroll
  for (int ds = 0; ds < 8; ++ds)
    aq[ds] = *reinterpret_cast<const bf16x8*>(qrow + ds * 16 + H * 8);

  f32x16 o[4];
#pragma unroll
  for (int db = 0; db < 4; ++db)
#pragma unroll
    for (int r = 0; r < 16; ++r) o[db][r] = 0.f;
  float m = -1e30f, l = 0.f;

  const int ntiles = (hist + q0 + 32 + 63) >> 6;

  auto STAGE = [&](int bufi, int kv0) {
#pragma unroll
    for (int c = 0; c < 2; ++c) {
      int ob = c * 8192 + tid * 16;
      int row = ob >> 8;
      int sp = (ob >> 4) & 15;
      const unsigned short* src = kseq_b + (size_t)(kv0 + row) * D_ + (((sp ^ (row & 15)) << 3));
      __builtin_amdgcn_global_load_lds((const __attribute__((address_space(1))) void*)src,
          (__attribute__((address_space(3))) void*)(&kl[bufi][c * 4096 + w * 512]), 16, 0, 0);
    }
#pragma unroll
    for (int c = 0; c < 2; ++c) {
      int ob = c * 8192 + tid * 16;
      int row = ob >> 7;
      int sp = (ob >> 4) & 7;
      const unsigned short* src = vtg_b + (size_t)row * KVC + kv0 + (((sp ^ (row & 7)) << 3));
      __builtin_amdgcn_global_load_lds((const __attribute__((address_space(1))) void*)src,
          (__attribute__((address_space(3))) void*)(&vt[bufi][c * 4096 + w * 512]), 16, 0, 0);
    }
  };

  STAGE(0, 0);
  __syncthreads();

  for (int it = 0; it < ntiles; ++it) {
    const int cur = it & 1;
    if (it + 1 < ntiles) STAGE(cur ^ 1, (it + 1) * 64);
    const unsigned short* kb = kl[cur];
    const unsigned short* vb = vt[cur];

    f32x16 sa = f32x16{0.f,0.f,0.f,0.f,0.f,0.f,0.f,0.f,0.f,0.f,0.f,0.f,0.f,0.f,0.f,0.f};
    f32x16 sb = sa, sc = sa, sd = sa;
#pragma unroll
    for (int ds = 0; ds < 4; ++ds) {
      const int sl = ((2 * ds + H) ^ (q & 15)) << 3;
      bf16x8 k0 = *reinterpret_cast<const bf16x8*>(kb + q * 128 + sl);
      bf16x8 k1 = *reinterpret_cast<const bf16x8*>(kb + (32 + q) * 128 + sl);
      sa = __builtin_amdgcn_mfma_f32_32x32x16_bf16(k0, aq[ds], sa, 0, 0, 0);
      sc = __builtin_amdgcn_mfma_f32_32x32x16_bf16(k1, aq[ds], sc, 0, 0, 0);
    }
#pragma unroll
    for (int ds = 4; ds < 8; ++ds) {
      const int sl = ((2 * ds + H) ^ (q & 15)) << 3;
      bf16x8 k0 = *reinterpret_cast<const bf16x8*>(kb + q * 128 + sl);
      bf16x8 k1 = *reinterpret_cast<const bf16x8*>(kb + (32 + q) * 128 + sl);
      sb = __builtin_amdgcn_mfma_f32_32x32x16_bf16(k0, aq[ds], sb, 0, 0, 0);
      sd = __builtin_amdgcn_mfma_f32_32x32x16_bf16(k1, aq[ds], sd, 0, 0, 0);
    }
    f32x16 s0 = sa + sb;
    f32x16 s1 = sc + sd;

    if (it == ntiles - 1) {
      const int limit = hist + q0 + q - it * 64 - 4 * H;
#pragma unroll
      for (int r = 0; r < 16; ++r) {
        const int koff = (r & 3) + 8 * ((r >> 2) & 1) + 16 * (r >> 3);
        if (koff > limit) s0[r] = -1e30f;
        if (32 + koff > limit) s1[r] = -1e30f;
      }
    }

    float pmax = s0[0];
#pragma unroll
    for (int r = 1; r < 16; ++r) pmax = fmaxf(pmax, s0[r]);
#pragma unroll
    for (int r = 0; r < 16; ++r) pmax = fmaxf(pmax, s1[r]);
    pmax = fmaxf(pmax, __shfl_xor(pmax, 32));
    if (__any(pmax > m + 11.54f)) {
      float mn = fmaxf(m, pmax);
      float al = exp2f(m - mn);
      m = mn;
      l *= al;
#pragma unroll
      for (int db = 0; db < 4; ++db)
#pragma unroll
        for (int r = 0; r < 16; ++r) o[db][r] *= al;
    }
    float rs = 0.f;
#pragma unroll
    for (int r = 0; r < 16; ++r) { s0[r] = exp2f(s0[r] - m); rs += s0[r]; }
#pragma unroll
    for (int r = 0; r < 16; ++r) { s1[r] = exp2f(s1[r] - m); rs += s1[r]; }
    rs += __shfl_xor(rs, 32);
    l += rs;

#pragma unroll
    for (int s = 0; s < 4; ++s) {
      float p0, p1, p2, p3, p4, p5, p6, p7;
      if (s == 0)      { p0=s0[0];p1=s0[1];p2=s0[2];p3=s0[3];p4=s0[4];p5=s0[5];p6=s0[6];p7=s0[7]; }
      else if (s == 1) { p0=s0[8];p1=s0[9];p2=s0[10];p3=s0[11];p4=s0[12];p5=s0[13];p6=s0[14];p7=s0[15]; }
      else if (s == 2) { p0=s1[0];p1=s1[1];p2=s1[2];p3=s1[3];p4=s1[4];p5=s1[5];p6=s1[6];p7=s1[7]; }
      else             { p0=s1[8];p1=s1[9];p2=s1[10];p3=s1[11];p4=s1[12];p5=s1[13];p6=s1[14];p7=s1[15]; }
      int c01 = cvtpk_bf16(p0, p1);
      int c23 = cvtpk_bf16(p2, p3);
      int c45 = cvtpk_bf16(p4, p5);
      int c67 = cvtpk_bf16(p6, p7);
      u32x2 rA = __builtin_amdgcn_permlane32_swap(c01, c45, false, false);
      u32x2 rB = __builtin_amdgcn_permlane32_swap(c23, c67, false, false);
      union { unsigned wds[4]; bf16x8 v; } uu;
      uu.wds[0] = rA[0]; uu.wds[1] = rB[0]; uu.wds[2] = rA[1]; uu.wds[3] = rB[1];
#pragma unroll
      for (int db = 0; db < 4; ++db) {
        const int row = db * 32 + q;
        bf16x8 vf = *reinterpret_cast<const bf16x8*>(vb + row * 64 + ((((2 * s + H) ^ (row & 7))) << 3));
        o[db] = __builtin_amdgcn_mfma_f32_32x32x16_bf16(vf, uu.v, o[db], 0, 0, 0);
      }
    }
    __syncthreads();
  }

  const float il = 1.f / l;
  unsigned short* orow = outb + (size_t)(b * Q_ + q0 + q) * (NH_ * D_) + h * D_;
#pragma unroll
  for (int db = 0; db < 4; ++db)
#pragma unroll
    for (int rr = 0; rr < 4; ++rr) {
      ushort4 st;
      st.x = f2bf(o[db][rr * 4 + 0] * il);
      st.y = f2bf(o[db][rr * 4 + 1] * il);
      st.z = f2bf(o[db][rr * 4 + 2] * il);
      st.w = f2bf(o[db][rr * 4 + 3] * il);
      *reinterpret_cast<ushort4*>(orow + db * 32 + rr * 8 + 4 * H) = st;
    }
}

extern "C" void kernel_launch(void* const* d_in, const int* in_sizes, int n_in,
                              void* d_out, int out_size, void* d_ws, size_t ws_size,
                              hipStream_t stream) {
  const float* hidden = (const float*)d_in[0];
  const float* qkvw   = (const float*)d_in[1];
  const float* densew = (const float*)d_in[2];
  const float* pk     = (const float*)d_in[3];
  const float* pv     = (const float*)d_in[4];
  const int* histL    = (const int*)d_in[7];
  const int* bo       = (const int*)d_in[8];
  const int* posids   = (const int*)d_in[9];
  float* out = (float*)d_out;

  char* ws = (char*)d_ws;
  unsigned short* ws_hidden = (unsigned short*)(ws);                    // 33.5 MB
  unsigned short* ws_w      = (unsigned short*)(ws + 33554432);         // 35.7 MB
  unsigned short* ws_fused  = (unsigned short*)(ws + 69206016);         // 35.7 MB
  unsigned short* ws_q      = (unsigned short*)(ws + 104857600);        // 33.5 MB
  unsigned short* ws_k      = (unsigned short*)(ws + 138412032);        // 4.2 MB
  unsigned short* ws_vt     = (unsigned short*)(ws + 142606336);        // 4.2 MB (transposed V)
  unsigned short* ws_attn   = ws_hidden;                                // reuse after GEMM1

  k_conv<<<2048, 256, 0, stream>>>(hidden, ws_hidden, T_ * HID_ / 4);
  k_conv<<<2048, 256, 0, stream>>>(qkvw, ws_w, QKVN * HID_ / 4);
  k_gemm256<<<dim3((T_ / 256) * (QKVN / 256)), 512, 131072, stream>>>(
      ws_hidden, ws_w, nullptr, ws_fused, T_ / 256, HID_, QKVN);
  k_rope<<<T_, 128, 0, stream>>>(ws_fused, posids, ws_q, ws_k, ws_vt);
  k_gather<<<B_ * (HIST_ / 64), 256, 0, stream>>>(pk, pv, bo, ws_k, ws_vt);
  dim3 ga(Q_ / 32, NH_ / 8, B_);
  k_attn<<<ga, 512, 0, stream>>>(ws_q, ws_k, ws_vt, histL, ws_attn);
  k_conv<<<2048, 256, 0, stream>>>(densew, ws_w, HID_ * HID_ / 4);
  k_gemm256<<<dim3((T_ / 256) * (HID_ / 256)), 512, 131072, stream>>>(
      ws_attn, ws_w, out, nullptr, T_ / 256, HID_, HID_);
}

// Round 6
// 549.043 us; speedup vs baseline: 2.1315x; 1.0302x over previous
//
#include <hip/hip_runtime.h>

typedef __attribute__((ext_vector_type(8))) short bf16x8;
typedef __attribute__((ext_vector_type(4))) float f32x4;
typedef __attribute__((ext_vector_type(16))) float f32x16;
typedef __attribute__((ext_vector_type(2))) unsigned int u32x2;

constexpr int B_ = 8, Q_ = 512, HIST_ = 1536, HID_ = 4096, NH_ = 32, D_ = 128;
constexpr int BS_ = 64, NBLK_ = 32;
constexpr int T_ = B_ * Q_;            // 4096
constexpr int QKVN = (NH_ + 2) * D_;   // 4352
constexpr int KVC = NBLK_ * BS_;       // 2048

__device__ __forceinline__ unsigned short f2bf(float f) {
  union { float f; unsigned u; } v; v.f = f;
  unsigned r = v.u + 0x7FFFu + ((v.u >> 16) & 1u);
  return (unsigned short)(r >> 16);
}
__device__ __forceinline__ float bf2f(unsigned short s) {
  union { unsigned u; float f; } v; v.u = ((unsigned)s) << 16;
  return v.f;
}
__device__ __forceinline__ int cvtpk_bf16(float lo, float hi) {
  int r;
  asm("v_cvt_pk_bf16_f32 %0, %1, %2" : "=v"(r) : "v"(lo), "v"(hi));
  return r;
}

// ---------------- f32 -> bf16 conversion (vectorized) ----------------
__global__ void k_conv(const float* __restrict__ in, unsigned short* __restrict__ out, int n4) {
  int i = blockIdx.x * blockDim.x + threadIdx.x;
  int stride = gridDim.x * blockDim.x;
  for (; i < n4; i += stride) {
    float4 v = reinterpret_cast<const float4*>(in)[i];
    ushort4 o;
    o.x = f2bf(v.x); o.y = f2bf(v.y); o.z = f2bf(v.z); o.w = f2bf(v.w);
    reinterpret_cast<ushort4*>(out)[i] = o;
  }
}

// ---------------- bf16 GEMM: 256x256, BK=64, FREE-RUNNING 2-barrier K-loop ----------------
// C[i,j] = sum_k A[i,k]*B[j,k]. 8 waves (2M x 4N), 512 thr, 128 KiB dbuf LDS.
// No per-phase barriers / lgkmcnt pins: compiler schedules ds_read->MFMA with
// fine-grained lgkmcnt; waves may drift within a K-tile half. Correctness needs
// only 2 barriers/tile, each right after a counted vmcnt(4):
//   mid-tile:  drains B(t+1) (read by all waves in phase B)
//   tile-end:  drains A(t+1) (read by all waves next tile)
// Stage targets never collide with in-tile reads (A(t+1)->other A-buf,
// B(t+2)->B-buf whose registers were consumed during tile t-1).
#define LDA4(af, cur_, qq)                                                              \
  {                                                                                     \
    const unsigned short* a_t = sA + (cur_) * 16384;                                    \
    const int r0 = wr * 128 + (qq) * 32 + lr;                                           \
    const int r1 = r0 + 16;                                                             \
    af[0][0] = *(const bf16x8*)&a_t[r0 * 64 + ((lk ^ (r0 & 7)) << 3)];                  \
    af[0][1] = *(const bf16x8*)&a_t[r0 * 64 + (((4 + lk) ^ (r0 & 7)) << 3)];            \
    af[1][0] = *(const bf16x8*)&a_t[r1 * 64 + ((lk ^ (r1 & 7)) << 3)];                  \
    af[1][1] = *(const bf16x8*)&a_t[r1 * 64 + (((4 + lk) ^ (r1 & 7)) << 3)];            \
  }

#define LDB2(dst, cur_, nn)                                                             \
  {                                                                                     \
    const unsigned short* b_t = sB + (cur_) * 16384;                                    \
    const int rb = wc * 64 + (nn) * 16 + lr;                                            \
    dst[nn][0] = *(const bf16x8*)&b_t[rb * 64 + ((lk ^ (rb & 7)) << 3)];                \
    dst[nn][1] = *(const bf16x8*)&b_t[rb * 64 + (((4 + lk) ^ (rb & 7)) << 3)];          \
  }

#define MFMA16(qq, af, Bf)                                                              \
  __builtin_amdgcn_s_setprio(1);                                                        \
  acc[(qq)*2+0][0] = __builtin_amdgcn_mfma_f32_16x16x32_bf16(af[0][0], Bf[0][0], acc[(qq)*2+0][0], 0, 0, 0); \
  acc[(qq)*2+0][1] = __builtin_amdgcn_mfma_f32_16x16x32_bf16(af[0][0], Bf[1][0], acc[(qq)*2+0][1], 0, 0, 0); \
  acc[(qq)*2+0][2] = __builtin_amdgcn_mfma_f32_16x16x32_bf16(af[0][0], Bf[2][0], acc[(qq)*2+0][2], 0, 0, 0); \
  acc[(qq)*2+0][3] = __builtin_amdgcn_mfma_f32_16x16x32_bf16(af[0][0], Bf[3][0], acc[(qq)*2+0][3], 0, 0, 0); \
  acc[(qq)*2+1][0] = __builtin_amdgcn_mfma_f32_16x16x32_bf16(af[1][0], Bf[0][0], acc[(qq)*2+1][0], 0, 0, 0); \
  acc[(qq)*2+1][1] = __builtin_amdgcn_mfma_f32_16x16x32_bf16(af[1][0], Bf[1][0], acc[(qq)*2+1][1], 0, 0, 0); \
  acc[(qq)*2+1][2] = __builtin_amdgcn_mfma_f32_16x16x32_bf16(af[1][0], Bf[2][0], acc[(qq)*2+1][2], 0, 0, 0); \
  acc[(qq)*2+1][3] = __builtin_amdgcn_mfma_f32_16x16x32_bf16(af[1][0], Bf[3][0], acc[(qq)*2+1][3], 0, 0, 0); \
  acc[(qq)*2+0][0] = __builtin_amdgcn_mfma_f32_16x16x32_bf16(af[0][1], Bf[0][1], acc[(qq)*2+0][0], 0, 0, 0); \
  acc[(qq)*2+0][1] = __builtin_amdgcn_mfma_f32_16x16x32_bf16(af[0][1], Bf[1][1], acc[(qq)*2+0][1], 0, 0, 0); \
  acc[(qq)*2+0][2] = __builtin_amdgcn_mfma_f32_16x16x32_bf16(af[0][1], Bf[2][1], acc[(qq)*2+0][2], 0, 0, 0); \
  acc[(qq)*2+0][3] = __builtin_amdgcn_mfma_f32_16x16x32_bf16(af[0][1], Bf[3][1], acc[(qq)*2+0][3], 0, 0, 0); \
  acc[(qq)*2+1][0] = __builtin_amdgcn_mfma_f32_16x16x32_bf16(af[1][1], Bf[0][1], acc[(qq)*2+1][0], 0, 0, 0); \
  acc[(qq)*2+1][1] = __builtin_amdgcn_mfma_f32_16x16x32_bf16(af[1][1], Bf[1][1], acc[(qq)*2+1][1], 0, 0, 0); \
  acc[(qq)*2+1][2] = __builtin_amdgcn_mfma_f32_16x16x32_bf16(af[1][1], Bf[2][1], acc[(qq)*2+1][2], 0, 0, 0); \
  acc[(qq)*2+1][3] = __builtin_amdgcn_mfma_f32_16x16x32_bf16(af[1][1], Bf[3][1], acc[(qq)*2+1][3], 0, 0, 0); \
  __builtin_amdgcn_s_setprio(0);

#define SYNCPT                                                                          \
  asm volatile("s_waitcnt vmcnt(4)" ::: "memory");                                      \
  __builtin_amdgcn_s_barrier();                                                         \
  asm volatile("" ::: "memory");

#define TILE(t_, cur_, BCUR, BNEXT)                                                     \
  {                                                                                     \
    bf16x8 af[2][2];                                                                    \
    /* half A: output quadrants 0,1 x full K=64; prefetch A(t+1) */                     \
    LDA4(af, cur_, 0);                                                                  \
    stage(A, m0, sA, (t_) + 1, 0);                                                      \
    MFMA16(0, af, BCUR);                                                                \
    LDA4(af, cur_, 1);                                                                  \
    stage(A, m0, sA, (t_) + 1, 1);                                                      \
    MFMA16(1, af, BCUR);                                                                \
    SYNCPT;  /* drains B(t+1) for everyone */                                           \
    /* half B: quadrants 2,3; B(t+1)->regs; prefetch B(t+2) */                          \
    LDA4(af, cur_, 2);                                                                  \
    LDB2(BNEXT, (cur_) ^ 1, 0); LDB2(BNEXT, (cur_) ^ 1, 1);                             \
    stage(Bm, n0, sB, (t_) + 2, 0);                                                     \
    MFMA16(2, af, BCUR);                                                                \
    LDA4(af, cur_, 3);                                                                  \
    LDB2(BNEXT, (cur_) ^ 1, 2); LDB2(BNEXT, (cur_) ^ 1, 3);                             \
    stage(Bm, n0, sB, (t_) + 2, 1);                                                     \
    MFMA16(3, af, BCUR);                                                                \
    SYNCPT;  /* drains A(t+1) for everyone */                                           \
  }

__global__ __launch_bounds__(512, 2) void k_gemm256(const unsigned short* __restrict__ A,
                          const unsigned short* __restrict__ Bm,
                          float* __restrict__ Cf, unsigned short* __restrict__ Cb,
                          int MB, int K, int ldc) {
  extern __shared__ unsigned short smem[];
  unsigned short* sA = smem;           // [2][256*64]
  unsigned short* sB = smem + 32768;   // [2][256*64]
  const int tid = threadIdx.x, lane = tid & 63, w = tid >> 6;
  const int wr = w >> 2, wc = w & 3;
  const int lr = lane & 15, lk = lane >> 4;

  // bijective XCD swizzle (m204)
  const int nwg = gridDim.x, orig = blockIdx.x;
  const int q8 = nwg >> 3, r8 = nwg & 7, xcd = orig & 7;
  const int wg = (xcd < r8 ? xcd * (q8 + 1) : r8 * (q8 + 1) + (xcd - r8) * q8) + (orig >> 3);
  const int m0 = (wg % MB) * 256;
  const int n0 = (wg / MB) * 256;
  const int NT = K >> 6;

  f32x4 acc[8][4];
#pragma unroll
  for (int mf = 0; mf < 8; ++mf)
#pragma unroll
    for (int nf = 0; nf < 4; ++nf) acc[mf][nf] = f32x4{0.f, 0.f, 0.f, 0.f};

  // stage one 16KB half-tile: linear LDS dest, inverse-swizzled global source
  auto stage = [&](const unsigned short* __restrict__ Mat, int rbase, unsigned short* regionBase,
                   int ts, int half) {
    const int di = ts < NT ? ts : NT - 1;   // clamp keeps the vmcnt ledger invariant at the tail
    const size_t k0 = (size_t)di << 6;
    char* hb = (char*)(regionBase + (ts & 1) * 16384 + half * 8192);
#pragma unroll
    for (int c = 0; c < 2; ++c) {
      const int ob = c * 8192 + (w << 10) + (lane << 4);  // byte offset within half
      const int row = ob >> 7;
      const int sl = ((ob >> 4) & 7) ^ (row & 7);
      const unsigned short* src = Mat + (size_t)(rbase + half * 128 + row) * K + k0 + sl * 8;
      __builtin_amdgcn_global_load_lds((const __attribute__((address_space(1))) void*)src,
          (__attribute__((address_space(3))) void*)(hb + c * 8192 + (w << 10)), 16, 0, 0);
    }
  };

  // prologue: A(0), B(0), B(1) staged (12 ops); vmcnt(4) drains A(0)+B(0), leaves B(1)
  stage(A, m0, sA, 0, 0); stage(A, m0, sA, 0, 1);
  stage(Bm, n0, sB, 0, 0); stage(Bm, n0, sB, 0, 1);
  stage(Bm, n0, sB, 1, 0); stage(Bm, n0, sB, 1, 1);
  asm volatile("s_waitcnt vmcnt(4)" ::: "memory");
  __builtin_amdgcn_s_barrier();
  asm volatile("" ::: "memory");
  bf16x8 bX[4][2], bY[4][2];
  LDB2(bX, 0, 0); LDB2(bX, 0, 1); LDB2(bX, 0, 2); LDB2(bX, 0, 3);

  for (int t = 0; t < NT; t += 2) {
    TILE(t, 0, bX, bY)
    TILE(t + 1, 1, bY, bX)
  }
  asm volatile("s_waitcnt vmcnt(0)" ::: "memory");

#pragma unroll
  for (int mf = 0; mf < 8; ++mf)
#pragma unroll
    for (int nf = 0; nf < 4; ++nf)
#pragma unroll
      for (int j = 0; j < 4; ++j) {
        const int rr = m0 + wr * 128 + mf * 16 + lk * 4 + j;
        const int cc = n0 + wc * 64 + nf * 16 + lr;
        if (Cb) Cb[(size_t)rr * ldc + cc] = f2bf(acc[mf][nf][j]);
        else Cf[(size_t)rr * ldc + cc] = acc[mf][nf][j];
      }
}

// ---------------- RoPE + repack: fused(T,4352) -> q (pre-scaled by log2e/sqrt(d)), kseq[b,kv,d], vtg[b,d,kv] ----------------
__global__ void k_rope(const unsigned short* __restrict__ fused,
                       const int* __restrict__ pos_ids,
                       unsigned short* __restrict__ qb,
                       unsigned short* __restrict__ kseq,
                       unsigned short* __restrict__ vtg) {
  int t = blockIdx.x;
  int d = threadIdx.x;  // 128 threads
  int b = t >> 9, q = t & 511;
  int pos = pos_ids[t];
  __shared__ float cs[64], sn[64];
  if (d < 64) {
    float inv = powf(10000.f, -(float)d * (1.f / 64.f));
    float ang = (float)pos * inv;
    cs[d] = cosf(ang);
    sn[d] = sinf(ang);
  }
  __syncthreads();
  // 1/sqrt(128) * log2(e): attention uses exp2
  const float scale = 0.1275174313836907f;
  float c = cs[d & 63], s = sn[d & 63];
  const unsigned short* row = fused + (size_t)t * QKVN;
#pragma unroll 4
  for (int h = 0; h < NH_; ++h) {
    float x = bf2f(row[h * D_ + d]);
    float xr = (d < 64) ? -bf2f(row[h * D_ + d + 64]) : bf2f(row[h * D_ + d - 64]);
    qb[(((size_t)(b * NH_ + h)) * Q_ + q) * D_ + d] = f2bf((x * c + xr * s) * scale);
  }
  {
    float x = bf2f(row[NH_ * D_ + d]);
    float xr = (d < 64) ? -bf2f(row[NH_ * D_ + d + 64]) : bf2f(row[NH_ * D_ + d - 64]);
    kseq[((size_t)b * KVC + pos) * D_ + d] = f2bf(x * c + xr * s);
  }
  vtg[((size_t)b * D_ + d) * KVC + pos] = row[(NH_ + 1) * D_ + d];
}

// ---------------- gather history KV: paged f32 cache -> kseq (row-major) + vtg (transposed) ----------------
__global__ void k_gather(const float* __restrict__ pk, const float* __restrict__ pv,
                         const int* __restrict__ bo,
                         unsigned short* __restrict__ kseq, unsigned short* __restrict__ vtg) {
  __shared__ unsigned short vl[64 * 140];
  const int ptile = blockIdx.x;              // B_ * (HIST_/64) = 192
  const int b = ptile / (HIST_ / 64);
  const int p0 = (ptile % (HIST_ / 64)) * 64;
  const int tid = threadIdx.x;
  const int blk = bo[b * NBLK_ + (p0 >> 6)];
#pragma unroll
  for (int c = 0; c < 8; ++c) {
    int u = c * 256 + tid;  // 64 p x 32 d4
    int p = u >> 5, d4 = u & 31;
    size_t src = ((size_t)blk * BS_ + p) * D_ + d4 * 4;
    float4 kv = *reinterpret_cast<const float4*>(pk + src);
    ushort4 ko;
    ko.x = f2bf(kv.x); ko.y = f2bf(kv.y); ko.z = f2bf(kv.z); ko.w = f2bf(kv.w);
    *reinterpret_cast<ushort4*>(kseq + ((size_t)b * KVC + p0 + p) * D_ + d4 * 4) = ko;
    float4 vv = *reinterpret_cast<const float4*>(pv + src);
    ushort4 vo;
    vo.x = f2bf(vv.x); vo.y = f2bf(vv.y); vo.z = f2bf(vv.z); vo.w = f2bf(vv.w);
    *reinterpret_cast<ushort4*>(&vl[p * 140 + d4 * 4]) = vo;
  }
  __syncthreads();
#pragma unroll
  for (int c = 0; c < 4; ++c) {
    int u = c * 256 + tid;  // 128 d x 8 pg
    int d = u >> 3, pg = u & 7;
    bf16x8 vv8;
#pragma unroll
    for (int i = 0; i < 8; ++i) vv8[i] = (short)vl[(pg * 8 + i) * 140 + d];
    *reinterpret_cast<bf16x8*>(vtg + ((size_t)b * D_ + d) * KVC + p0 + pg * 8) = vv8;
  }
}

// ---------------- MQA flash attention, 8-wave swapped-QK^T (m214/T12 structure) ----------------
__global__ __launch_bounds__(512, 2) void k_attn(const unsigned short* __restrict__ qb,
                       const unsigned short* __restrict__ kseq,
                       const unsigned short* __restrict__ vtg,
                       const int* __restrict__ histL,
                       unsigned short* __restrict__ outb) {
  __shared__ alignas(16) unsigned short kl[2][64 * 128];  // [kv 64][d 128], slot^=(row&15)
  __shared__ alignas(16) unsigned short vt[2][128 * 64];  // [d 128][kv 64], slot^=(row&7)
  const int qt = blockIdx.x, hp = blockIdx.y, b = blockIdx.z;
  const int tid = threadIdx.x, lane = tid & 63, w = tid >> 6;
  const int H = lane >> 5, q = lane & 31;
  const int h = hp * 8 + w;
  const int q0 = qt * 32;
  const int hist = histL[b];
  const unsigned short* kseq_b = kseq + (size_t)b * KVC * D_;
  const unsigned short* vtg_b  = vtg + (size_t)b * D_ * KVC;

  const unsigned short* qrow = qb + (((size_t)(b * NH_ + h)) * Q_ + q0 + q) * D_;
  bf16x8 aq[8];
#pragma unroll
  for (int ds = 0; ds < 8; ++ds)
    aq[ds] = *reinterpret_cast<const bf16x8*>(qrow + ds * 16 + H * 8);

  f32x16 o[4];
#pragma unroll
  for (int db = 0; db < 4; ++db)
#pragma unroll
    for (int r = 0; r < 16; ++r) o[db][r] = 0.f;
  float m = -1e30f, l = 0.f;

  const int ntiles = (hist + q0 + 32 + 63) >> 6;

  auto STAGE = [&](int bufi, int kv0) {
#pragma unroll
    for (int c = 0; c < 2; ++c) {
      int ob = c * 8192 + tid * 16;
      int row = ob >> 8;
      int sp = (ob >> 4) & 15;
      const unsigned short* src = kseq_b + (size_t)(kv0 + row) * D_ + (((sp ^ (row & 15)) << 3));
      __builtin_amdgcn_global_load_lds((const __attribute__((address_space(1))) void*)src,
          (__attribute__((address_space(3))) void*)(&kl[bufi][c * 4096 + w * 512]), 16, 0, 0);
    }
#pragma unroll
    for (int c = 0; c < 2; ++c) {
      int ob = c * 8192 + tid * 16;
      int row = ob >> 7;
      int sp = (ob >> 4) & 7;
      const unsigned short* src = vtg_b + (size_t)row * KVC + kv0 + (((sp ^ (row & 7)) << 3));
      __builtin_amdgcn_global_load_lds((const __attribute__((address_space(1))) void*)src,
          (__attribute__((address_space(3))) void*)(&vt[bufi][c * 4096 + w * 512]), 16, 0, 0);
    }
  };

  STAGE(0, 0);
  __syncthreads();

  for (int it = 0; it < ntiles; ++it) {
    const int cur = it & 1;
    if (it + 1 < ntiles) STAGE(cur ^ 1, (it + 1) * 64);
    const unsigned short* kb = kl[cur];
    const unsigned short* vb = vt[cur];

    f32x16 sa = f32x16{0.f,0.f,0.f,0.f,0.f,0.f,0.f,0.f,0.f,0.f,0.f,0.f,0.f,0.f,0.f,0.f};
    f32x16 sb = sa, sc = sa, sd = sa;
#pragma unroll
    for (int ds = 0; ds < 4; ++ds) {
      const int sl = ((2 * ds + H) ^ (q & 15)) << 3;
      bf16x8 k0 = *reinterpret_cast<const bf16x8*>(kb + q * 128 + sl);
      bf16x8 k1 = *reinterpret_cast<const bf16x8*>(kb + (32 + q) * 128 + sl);
      sa = __builtin_amdgcn_mfma_f32_32x32x16_bf16(k0, aq[ds], sa, 0, 0, 0);
      sc = __builtin_amdgcn_mfma_f32_32x32x16_bf16(k1, aq[ds], sc, 0, 0, 0);
    }
#pragma unroll
    for (int ds = 4; ds < 8; ++ds) {
      const int sl = ((2 * ds + H) ^ (q & 15)) << 3;
      bf16x8 k0 = *reinterpret_cast<const bf16x8*>(kb + q * 128 + sl);
      bf16x8 k1 = *reinterpret_cast<const bf16x8*>(kb + (32 + q) * 128 + sl);
      sb = __builtin_amdgcn_mfma_f32_32x32x16_bf16(k0, aq[ds], sb, 0, 0, 0);
      sd = __builtin_amdgcn_mfma_f32_32x32x16_bf16(k1, aq[ds], sd, 0, 0, 0);
    }
    f32x16 s0 = sa + sb;
    f32x16 s1 = sc + sd;

    if (it == ntiles - 1) {
      const int limit = hist + q0 + q - it * 64 - 4 * H;
#pragma unroll
      for (int r = 0; r < 16; ++r) {
        const int koff = (r & 3) + 8 * ((r >> 2) & 1) + 16 * (r >> 3);
        if (koff > limit) s0[r] = -1e30f;
        if (32 + koff > limit) s1[r] = -1e30f;
      }
    }

    float pmax = s0[0];
#pragma unroll
    for (int r = 1; r < 16; ++r) pmax = fmaxf(pmax, s0[r]);
#pragma unroll
    for (int r = 0; r < 16; ++r) pmax = fmaxf(pmax, s1[r]);
    pmax = fmaxf(pmax, __shfl_xor(pmax, 32));
    if (__any(pmax > m + 11.54f)) {
      float mn = fmaxf(m, pmax);
      float al = exp2f(m - mn);
      m = mn;
      l *= al;
#pragma unroll
      for (int db = 0; db < 4; ++db)
#pragma unroll
        for (int r = 0; r < 16; ++r) o[db][r] *= al;
    }
    float rs = 0.f;
#pragma unroll
    for (int r = 0; r < 16; ++r) { s0[r] = exp2f(s0[r] - m); rs += s0[r]; }
#pragma unroll
    for (int r = 0; r < 16; ++r) { s1[r] = exp2f(s1[r] - m); rs += s1[r]; }
    rs += __shfl_xor(rs, 32);
    l += rs;

#pragma unroll
    for (int s = 0; s < 4; ++s) {
      float p0, p1, p2, p3, p4, p5, p6, p7;
      if (s == 0)      { p0=s0[0];p1=s0[1];p2=s0[2];p3=s0[3];p4=s0[4];p5=s0[5];p6=s0[6];p7=s0[7]; }
      else if (s == 1) { p0=s0[8];p1=s0[9];p2=s0[10];p3=s0[11];p4=s0[12];p5=s0[13];p6=s0[14];p7=s0[15]; }
      else if (s == 2) { p0=s1[0];p1=s1[1];p2=s1[2];p3=s1[3];p4=s1[4];p5=s1[5];p6=s1[6];p7=s1[7]; }
      else             { p0=s1[8];p1=s1[9];p2=s1[10];p3=s1[11];p4=s1[12];p5=s1[13];p6=s1[14];p7=s1[15]; }
      int c01 = cvtpk_bf16(p0, p1);
      int c23 = cvtpk_bf16(p2, p3);
      int c45 = cvtpk_bf16(p4, p5);
      int c67 = cvtpk_bf16(p6, p7);
      u32x2 rA = __builtin_amdgcn_permlane32_swap(c01, c45, false, false);
      u32x2 rB = __builtin_amdgcn_permlane32_swap(c23, c67, false, false);
      union { unsigned wds[4]; bf16x8 v; } uu;
      uu.wds[0] = rA[0]; uu.wds[1] = rB[0]; uu.wds[2] = rA[1]; uu.wds[3] = rB[1];
#pragma unroll
      for (int db = 0; db < 4; ++db) {
        const int row = db * 32 + q;
        bf16x8 vf = *reinterpret_cast<const bf16x8*>(vb + row * 64 + ((((2 * s + H) ^ (row & 7))) << 3));
        o[db] = __builtin_amdgcn_mfma_f32_32x32x16_bf16(vf, uu.v, o[db], 0, 0, 0);
      }
    }
    __syncthreads();
  }

  const float il = 1.f / l;
  unsigned short* orow = outb + (size_t)(b * Q_ + q0 + q) * (NH_ * D_) + h * D_;
#pragma unroll
  for (int db = 0; db < 4; ++db)
#pragma unroll
    for (int rr = 0; rr < 4; ++rr) {
      ushort4 st;
      st.x = f2bf(o[db][rr * 4 + 0] * il);
      st.y = f2bf(o[db][rr * 4 + 1] * il);
      st.z = f2bf(o[db][rr * 4 + 2] * il);
      st.w = f2bf(o[db][rr * 4 + 3] * il);
      *reinterpret_cast<ushort4*>(orow + db * 32 + rr * 8 + 4 * H) = st;
    }
}

extern "C" void kernel_launch(void* const* d_in, const int* in_sizes, int n_in,
                              void* d_out, int out_size, void* d_ws, size_t ws_size,
                              hipStream_t stream) {
  const float* hidden = (const float*)d_in[0];
  const float* qkvw   = (const float*)d_in[1];
  const float* densew = (const float*)d_in[2];
  const float* pk     = (const float*)d_in[3];
  const float* pv     = (const float*)d_in[4];
  const int* histL    = (const int*)d_in[7];
  const int* bo       = (const int*)d_in[8];
  const int* posids   = (const int*)d_in[9];
  float* out = (float*)d_out;

  char* ws = (char*)d_ws;
  unsigned short* ws_hidden = (unsigned short*)(ws);                    // 33.5 MB
  unsigned short* ws_w      = (unsigned short*)(ws + 33554432);         // 35.7 MB
  unsigned short* ws_fused  = (unsigned short*)(ws + 69206016);         // 35.7 MB
  unsigned short* ws_q      = (unsigned short*)(ws + 104857600);        // 33.5 MB
  unsigned short* ws_k      = (unsigned short*)(ws + 138412032);        // 4.2 MB
  unsigned short* ws_vt     = (unsigned short*)(ws + 142606336);        // 4.2 MB (transposed V)
  unsigned short* ws_attn   = ws_hidden;                                // reuse after GEMM1

  k_conv<<<2048, 256, 0, stream>>>(hidden, ws_hidden, T_ * HID_ / 4);
  k_conv<<<2048, 256, 0, stream>>>(qkvw, ws_w, QKVN * HID_ / 4);
  k_gemm256<<<dim3((T_ / 256) * (QKVN / 256)), 512, 131072, stream>>>(
      ws_hidden, ws_w, nullptr, ws_fused, T_ / 256, HID_, QKVN);
  k_rope<<<T_, 128, 0, stream>>>(ws_fused, posids, ws_q, ws_k, ws_vt);
  k_gather<<<B_ * (HIST_ / 64), 256, 0, stream>>>(pk, pv, bo, ws_k, ws_vt);
  dim3 ga(Q_ / 32, NH_ / 8, B_);
  k_attn<<<ga, 512, 0, stream>>>(ws_q, ws_k, ws_vt, histL, ws_attn);
  k_conv<<<2048, 256, 0, stream>>>(densew, ws_w, HID_ * HID_ / 4);
  k_gemm256<<<dim3((T_ / 256) * (HID_ / 256)), 512, 131072, stream>>>(
      ws_attn, ws_w, out, nullptr, T_ / 256, HID_, HID_);
}